// Round 4
// baseline (4456.765 us; speedup 1.0000x reference)
//
#include <hip/hip_runtime.h>
#include <cstdint>
#include <cstddef>

#define HCH 192
#define ICH 64
#define NRAD 6
#define SBFD 42

constexpr int NT = 256;

using bfrag = __attribute__((ext_vector_type(8))) short;  // 8 bf16 (4 VGPRs)
using f32x4 = __attribute__((ext_vector_type(4))) float;

#define MFMA16(a, b, c) __builtin_amdgcn_mfma_f32_16x16x32_bf16(a, b, c, 0, 0, 0)

__device__ __forceinline__ float silu_f(float v) {
    return v / (1.0f + __expf(-v));
}

__device__ __forceinline__ unsigned short f2bf(float x) {
    union { float f; unsigned u; } v; v.f = x;
    return (unsigned short)((v.u + 0x7FFFu + ((v.u >> 16) & 1u)) >> 16);
}

__device__ __forceinline__ float bf2f(unsigned short u) {
    union { unsigned u; float f; } v; v.u = ((unsigned)u) << 16;
    return v.f;
}

__device__ __forceinline__ bfrag pack8(float4 a, float4 b) {
    bfrag r;
    r[0] = (short)f2bf(a.x); r[1] = (short)f2bf(a.y);
    r[2] = (short)f2bf(a.z); r[3] = (short)f2bf(a.w);
    r[4] = (short)f2bf(b.x); r[5] = (short)f2bf(b.y);
    r[6] = (short)f2bf(b.z); r[7] = (short)f2bf(b.w);
    return r;
}

// ---------------- weight prep: fp32 [K][N] -> bf16 transposed [N][K] ----------------
// Wt layout: 9 x (192x192) [kj, ji, lin, rb0_0, rb0_1, ra0_0, ra0_1, ra1_0, ra1_1]
// then down [64][192], then up [192][64]
#define WSEG 36864
#define WT_DOWN (9 * WSEG)
#define WT_UP   (9 * WSEG + 12288)
#define WT_TOTAL (9 * WSEG + 2 * 12288)

__global__ __launch_bounds__(NT) void prep_k(
    const float* __restrict__ W_kj, const float* __restrict__ W_ji,
    const float* __restrict__ W_lin, const float* __restrict__ resbW,
    const float* __restrict__ resaW, const float* __restrict__ W_down,
    const float* __restrict__ W_up, unsigned short* __restrict__ Wt)
{
    int i = blockIdx.x * NT + threadIdx.x;
    if (i < 9 * WSEG) {
        int seg = i / WSEG, r = i % WSEG;
        int k = r / HCH, n = r % HCH;
        const float* src =
            seg == 0 ? W_kj : seg == 1 ? W_ji : seg == 2 ? W_lin :
            seg <= 4 ? resbW + (seg - 3) * WSEG : resaW + (seg - 5) * WSEG;
        Wt[seg * WSEG + n * HCH + k] = f2bf(src[r]);
    } else if (i < WT_DOWN + 12288) {
        int r = i - WT_DOWN;
        int k = r / ICH, n = r % ICH;           // W_down [192][64]
        Wt[WT_DOWN + n * HCH + k] = f2bf(W_down[r]);
    } else if (i < WT_TOTAL) {
        int r = i - WT_UP;
        int k = r / HCH, n = r % HCH;           // W_up [64][192]
        Wt[WT_UP + n * ICH + k] = f2bf(W_up[r]);
    }
}

// wc_rbf[6,192] = W_rbf1[6,8] @ W_rbf2[8,192]  (kept fp32)
__global__ void wc_k(const float* __restrict__ W_rbf1, const float* __restrict__ W_rbf2,
                     float* __restrict__ wc)
{
    int tid = blockIdx.x * blockDim.x + threadIdx.x;
    if (tid < NRAD * HCH) {
        int r = tid / HCH, c = tid % HCH;
        float a = 0.f;
        #pragma unroll
        for (int b = 0; b < 8; ++b) a += W_rbf1[r * 8 + b] * W_rbf2[b * HCH + c];
        wc[tid] = a;
    }
}

// ---------------- head: x -> x64b (bf16) : W_kj + rbf modulate + W_down ----------------
__global__ __launch_bounds__(NT) void fused12_k(
    const float* __restrict__ x, const unsigned short* __restrict__ Wt_kj,
    const float* __restrict__ b_kj, const float* __restrict__ rbf,
    const float* __restrict__ wc, const unsigned short* __restrict__ Wt_down,
    unsigned short* __restrict__ x64b, int E)
{
    __shared__ unsigned short u_s[64][200];
    __shared__ float wc_s[NRAD * HCH];
    const int tid = threadIdx.x;
    const int lane = tid & 63, w = tid >> 6;
    const int row0 = blockIdx.x * 64;
    const int lr = lane & 15, lq = lane >> 4;
    const int kq = lq * 8;

    for (int i = tid; i < NRAD * HCH; i += NT) wc_s[i] = wc[i];

    const int ra = row0 + w * 16 + lr;
    const bool rav = ra < E;

    f32x4 acc[12];
    #pragma unroll
    for (int t = 0; t < 12; ++t) acc[t] = (f32x4){0.f, 0.f, 0.f, 0.f};

    #pragma unroll
    for (int ks = 0; ks < 6; ++ks) {
        const int k0 = ks * 32;
        float4 a0 = make_float4(0,0,0,0), a1 = make_float4(0,0,0,0);
        if (rav) {
            a0 = *(const float4*)(x + (size_t)ra * HCH + k0 + kq);
            a1 = *(const float4*)(x + (size_t)ra * HCH + k0 + kq + 4);
        }
        bfrag a = pack8(a0, a1);
        #pragma unroll
        for (int t = 0; t < 12; ++t) {
            bfrag b = *(const bfrag*)(Wt_kj + (size_t)(t * 16 + lr) * HCH + k0 + kq);
            acc[t] = MFMA16(a, b, acc[t]);
        }
    }
    __syncthreads();   // wc_s ready
    #pragma unroll
    for (int r = 0; r < 4; ++r) {
        int rloc = lq * 4 + r;
        int grow = row0 + w * 16 + rloc;
        float rb[NRAD];
        #pragma unroll
        for (int q = 0; q < NRAD; ++q) rb[q] = 0.f;
        if (grow < E) {
            #pragma unroll
            for (int q = 0; q < NRAD; ++q) rb[q] = rbf[(size_t)grow * NRAD + q];
        }
        #pragma unroll
        for (int t = 0; t < 12; ++t) {
            int col = t * 16 + lr;
            float sv = silu_f(acc[t][r] + b_kj[col]);
            float rh = 0.f;
            #pragma unroll
            for (int q = 0; q < NRAD; ++q) rh += rb[q] * wc_s[q * HCH + col];
            u_s[w * 16 + rloc][col] = f2bf(sv * rh);
        }
    }
    __syncthreads();   // u_s visible (cross-lane)

    f32x4 acc2[4];
    #pragma unroll
    for (int t = 0; t < 4; ++t) acc2[t] = (f32x4){0.f, 0.f, 0.f, 0.f};
    #pragma unroll
    for (int ks = 0; ks < 6; ++ks) {
        const int k0 = ks * 32;
        bfrag a = *(const bfrag*)&u_s[w * 16 + lr][k0 + kq];
        #pragma unroll
        for (int t = 0; t < 4; ++t) {
            bfrag b = *(const bfrag*)(Wt_down + (size_t)(t * 16 + lr) * HCH + k0 + kq);
            acc2[t] = MFMA16(a, b, acc2[t]);
        }
    }
    #pragma unroll
    for (int r = 0; r < 4; ++r) {
        int grow = row0 + w * 16 + lq * 4 + r;
        if (grow >= E) continue;
        #pragma unroll
        for (int t = 0; t < 4; ++t)
            x64b[(size_t)grow * ICH + t * 16 + lr] = f2bf(silu_f(acc2[t][r]));
    }
}

// ---------------- fused tail: combine + res_b0 + lin + res_a0 + res_a1 ----------------
// Each 64-row block chains 8 GEMMs. h carried fp32 in registers (C layout);
// bf16 A-operands bounced via two alternating LDS buffers.
__global__ __launch_bounds__(NT) void tail_k(
    const float* __restrict__ x, const float* __restrict__ agg,
    const unsigned short* __restrict__ Wt_ji, const float* __restrict__ b_ji,
    const unsigned short* __restrict__ Wt_up,
    const unsigned short* __restrict__ Wt_rb0, const float* __restrict__ rbB,
    const unsigned short* __restrict__ Wt_lin, const float* __restrict__ b_lin,
    const unsigned short* __restrict__ Wt_ra, const float* __restrict__ raB,
    float* __restrict__ out, int E)
{
    __shared__ unsigned short bufA[64][200];
    __shared__ unsigned short bufB[64][200];
    const int tid = threadIdx.x;
    const int lane = tid & 63, w = tid >> 6;
    const int row0 = blockIdx.x * 64;
    const int lr = lane & 15, lq = lane >> 4;
    const int kq = lq * 8;
    const int ra = row0 + w * 16 + lr;
    const bool rav = ra < E;

    float hreg[12][4];
    f32x4 acc[12];

    // ---- stage 0a: acc = agg @ W_up ; hreg = silu(acc) ----
    #pragma unroll
    for (int t = 0; t < 12; ++t) acc[t] = (f32x4){0.f, 0.f, 0.f, 0.f};
    #pragma unroll
    for (int ks = 0; ks < 2; ++ks) {
        const int k0 = ks * 32;
        float4 a0 = make_float4(0,0,0,0), a1 = make_float4(0,0,0,0);
        if (rav) {
            a0 = *(const float4*)(agg + (size_t)ra * ICH + k0 + kq);
            a1 = *(const float4*)(agg + (size_t)ra * ICH + k0 + kq + 4);
        }
        bfrag a = pack8(a0, a1);
        #pragma unroll
        for (int t = 0; t < 12; ++t) {
            bfrag b = *(const bfrag*)(Wt_up + (size_t)(t * 16 + lr) * ICH + k0 + kq);
            acc[t] = MFMA16(a, b, acc[t]);
        }
    }
    #pragma unroll
    for (int t = 0; t < 12; ++t)
        #pragma unroll
        for (int r = 0; r < 4; ++r) hreg[t][r] = silu_f(acc[t][r]);

    // ---- stage 0b: acc = x @ W_ji ; hreg += silu(acc + b_ji); write h -> bufA ----
    #pragma unroll
    for (int t = 0; t < 12; ++t) acc[t] = (f32x4){0.f, 0.f, 0.f, 0.f};
    #pragma unroll
    for (int ks = 0; ks < 6; ++ks) {
        const int k0 = ks * 32;
        float4 a0 = make_float4(0,0,0,0), a1 = make_float4(0,0,0,0);
        if (rav) {
            a0 = *(const float4*)(x + (size_t)ra * HCH + k0 + kq);
            a1 = *(const float4*)(x + (size_t)ra * HCH + k0 + kq + 4);
        }
        bfrag a = pack8(a0, a1);
        #pragma unroll
        for (int t = 0; t < 12; ++t) {
            bfrag b = *(const bfrag*)(Wt_ji + (size_t)(t * 16 + lr) * HCH + k0 + kq);
            acc[t] = MFMA16(a, b, acc[t]);
        }
    }
    #pragma unroll
    for (int t = 0; t < 12; ++t) {
        int col = t * 16 + lr;
        float bb = b_ji[col];
        #pragma unroll
        for (int r = 0; r < 4; ++r) {
            hreg[t][r] += silu_f(acc[t][r] + bb);
            bufA[w * 16 + lq * 4 + r][col] = f2bf(hreg[t][r]);
        }
    }
    __syncthreads();

    // GEMM from LDS buffer
#define GEMM_LDS(SRC, WSEGP)                                                     \
    {                                                                            \
        _Pragma("unroll")                                                        \
        for (int t = 0; t < 12; ++t) acc[t] = (f32x4){0.f, 0.f, 0.f, 0.f};       \
        _Pragma("unroll")                                                        \
        for (int ks = 0; ks < 6; ++ks) {                                         \
            bfrag a = *(const bfrag*)&SRC[w * 16 + lr][ks * 32 + kq];            \
            _Pragma("unroll")                                                    \
            for (int t = 0; t < 12; ++t) {                                       \
                bfrag b = *(const bfrag*)((WSEGP) +                              \
                          (size_t)(t * 16 + lr) * HCH + ks * 32 + kq);           \
                acc[t] = MFMA16(a, b, acc[t]);                                   \
            }                                                                    \
        }                                                                        \
    }
    // t-stage: DST = silu(acc + bias)
#define EPI_T(DST, BIASP)                                                        \
    {                                                                            \
        _Pragma("unroll")                                                        \
        for (int t = 0; t < 12; ++t) {                                           \
            int col = t * 16 + lr;                                               \
            float bb = (BIASP)[col];                                             \
            _Pragma("unroll")                                                    \
            for (int r = 0; r < 4; ++r)                                          \
                DST[w * 16 + lq * 4 + r][col] = f2bf(silu_f(acc[t][r] + bb));    \
        }                                                                        \
    }
    // h-stage: hreg += silu(acc + bias); DST = bf16(hreg)
#define EPI_H(DST, BIASP)                                                        \
    {                                                                            \
        _Pragma("unroll")                                                        \
        for (int t = 0; t < 12; ++t) {                                           \
            int col = t * 16 + lr;                                               \
            float bb = (BIASP)[col];                                             \
            _Pragma("unroll")                                                    \
            for (int r = 0; r < 4; ++r) {                                        \
                hreg[t][r] += silu_f(acc[t][r] + bb);                            \
                DST[w * 16 + lq * 4 + r][col] = f2bf(hreg[t][r]);                \
            }                                                                    \
        }                                                                        \
    }

    // ---- res_before layer 0 ----
    GEMM_LDS(bufA, Wt_rb0);            EPI_T(bufB, rbB);            __syncthreads();
    GEMM_LDS(bufB, Wt_rb0 + WSEG);     EPI_H(bufA, rbB + HCH);      __syncthreads();

    // ---- lin: hreg = silu(acc + b_lin) + x ----
    GEMM_LDS(bufA, Wt_lin);
    #pragma unroll
    for (int t = 0; t < 12; ++t) {
        int col = t * 16 + lr;
        float bb = b_lin[col];
        #pragma unroll
        for (int r = 0; r < 4; ++r) {
            int grow = row0 + w * 16 + lq * 4 + r;
            float xv = (grow < E) ? x[(size_t)grow * HCH + col] : 0.f;
            hreg[t][r] = silu_f(acc[t][r] + bb) + xv;
            bufB[w * 16 + lq * 4 + r][col] = f2bf(hreg[t][r]);
        }
    }
    __syncthreads();

    // ---- res_after layer 0 ----
    GEMM_LDS(bufB, Wt_ra);             EPI_T(bufA, raB);            __syncthreads();
    GEMM_LDS(bufA, Wt_ra + WSEG);      EPI_H(bufB, raB + HCH);      __syncthreads();
    // ---- res_after layer 1 ----
    GEMM_LDS(bufB, Wt_ra + 2 * WSEG);  EPI_T(bufA, raB + 2 * HCH);  __syncthreads();
    GEMM_LDS(bufA, Wt_ra + 3 * WSEG);
    #pragma unroll
    for (int t = 0; t < 12; ++t) {
        int col = t * 16 + lr;
        float bb = raB[3 * HCH + col];
        #pragma unroll
        for (int r = 0; r < 4; ++r) {
            int grow = row0 + w * 16 + lq * 4 + r;
            if (grow < E)
                out[(size_t)grow * HCH + col] = hreg[t][r] + silu_f(acc[t][r] + bb);
        }
    }
}

// ---------------- CSR scatter->gather pipeline ----------------
__global__ __launch_bounds__(256) void pcount_k(
    const float* __restrict__ sbf, const int* __restrict__ idx_ji,
    const float* __restrict__ w1, unsigned short* __restrict__ pB,
    int* __restrict__ counts, int T)
{
    int t = blockIdx.x * 256 + threadIdx.x;
    if (t >= T) return;
    const float* sp = sbf + (size_t)t * SBFD;
    float acc[8];
    #pragma unroll
    for (int b = 0; b < 8; ++b) acc[b] = 0.f;
    #pragma unroll
    for (int r = 0; r < SBFD; r += 2) {
        float2 v = *(const float2*)(sp + r);
        #pragma unroll
        for (int b = 0; b < 8; ++b)
            acc[b] += v.x * w1[r * 8 + b] + v.y * w1[(r + 1) * 8 + b];
    }
    uint4 pk;
    pk.x = (unsigned)f2bf(acc[0]) | ((unsigned)f2bf(acc[1]) << 16);
    pk.y = (unsigned)f2bf(acc[2]) | ((unsigned)f2bf(acc[3]) << 16);
    pk.z = (unsigned)f2bf(acc[4]) | ((unsigned)f2bf(acc[5]) << 16);
    pk.w = (unsigned)f2bf(acc[6]) | ((unsigned)f2bf(acc[7]) << 16);
    *(uint4*)(pB + (size_t)t * 8) = pk;
    atomicAdd(&counts[idx_ji[t]], 1);
}

__global__ __launch_bounds__(256) void psum1_k(const int* __restrict__ counts,
                                               int* __restrict__ bsum, int E) {
    __shared__ int s[256];
    int base = blockIdx.x * 1024;
    int tid = threadIdx.x;
    int sum = 0;
    #pragma unroll
    for (int j = 0; j < 4; ++j) { int i = base + j * 256 + tid; if (i < E) sum += counts[i]; }
    s[tid] = sum; __syncthreads();
    for (int off = 128; off > 0; off >>= 1) {
        if (tid < off) s[tid] += s[tid + off];
        __syncthreads();
    }
    if (tid == 0) bsum[blockIdx.x] = s[0];
}

__global__ __launch_bounds__(512) void psum2_k(int* bsum, int G) {
    __shared__ int s[512];
    int tid = threadIdx.x;
    s[tid] = (tid < G) ? bsum[tid] : 0;
    for (int off = 1; off < 512; off <<= 1) {
        __syncthreads();
        int v = (tid >= off) ? s[tid - off] : 0;
        __syncthreads();
        s[tid] += v;
    }
    __syncthreads();
    if (tid < G) bsum[tid] = (tid == 0) ? 0 : s[tid - 1];
}

__global__ __launch_bounds__(256) void psum3_k(const int* __restrict__ counts,
                                               const int* __restrict__ bsum,
                                               int* __restrict__ start, int E) {
    __shared__ int s[256];
    int tid = threadIdx.x;
    int base = blockIdx.x * 1024 + tid * 4;
    int v[4]; int loc = 0;
    #pragma unroll
    for (int j = 0; j < 4; ++j) { v[j] = (base + j < E) ? counts[base + j] : 0; loc += v[j]; }
    s[tid] = loc;
    for (int off = 1; off < 256; off <<= 1) {
        __syncthreads();
        int t2 = (tid >= off) ? s[tid - off] : 0;
        __syncthreads();
        s[tid] += t2;
    }
    __syncthreads();
    int run = bsum[blockIdx.x] + s[tid] - loc;
    #pragma unroll
    for (int j = 0; j < 4; ++j) { if (base + j < E) start[base + j] = run; run += v[j]; }
}

__global__ __launch_bounds__(256) void fill_k(const int* __restrict__ idx_ji,
                                              int* __restrict__ start,
                                              int* __restrict__ trip, int T) {
    int t = blockIdx.x * 256 + threadIdx.x;
    if (t >= T) return;
    int pos = atomicAdd(&start[idx_ji[t]], 1);
    trip[pos] = t;
}

__global__ __launch_bounds__(256) void gather_k(
    const int* __restrict__ trip, const int* __restrict__ idx_kj,
    const unsigned short* __restrict__ pB, const unsigned short* __restrict__ x64b,
    const int* __restrict__ start, const int* __restrict__ counts,
    const float* __restrict__ w2, float* __restrict__ agg, int E)
{
    __shared__ float w2s[8 * 64];
    int tid = threadIdx.x;
    for (int i = tid; i < 8 * 64; i += 256) w2s[i] = w2[i];
    __syncthreads();

    int wave = (blockIdx.x * 256 + tid) >> 6;
    int lane = tid & 63;
    if (wave >= E) return;

    int n = counts[wave];
    int end = start[wave];
    int begin = end - n;

    float acc = 0.f;
    for (int i = begin; i < end; ++i) {
        int t = trip[i];
        int kj = idx_kj[t];
        float p8 = bf2f(pB[(size_t)t * 8 + (lane & 7)]);
        float xv = bf2f(x64b[(size_t)kj * ICH + lane]);
        float sc = 0.f;
        #pragma unroll
        for (int b = 0; b < 8; ++b)
            sc += __shfl(p8, b, 64) * w2s[b * 64 + lane];
        acc += sc * xv;
    }
    agg[(size_t)wave * ICH + lane] = acc;
}

extern "C" void kernel_launch(void* const* d_in, const int* in_sizes, int n_in,
                              void* d_out, int out_size, void* d_ws, size_t ws_size,
                              hipStream_t stream) {
    const float* x      = (const float*)d_in[0];
    const float* rbf    = (const float*)d_in[1];
    const float* sbf    = (const float*)d_in[2];
    const int*   idx_kj = (const int*)d_in[3];
    const int*   idx_ji = (const int*)d_in[4];
    const float* W_rbf1 = (const float*)d_in[5];
    const float* W_rbf2 = (const float*)d_in[6];
    const float* W_sbf1 = (const float*)d_in[7];
    const float* W_sbf2 = (const float*)d_in[8];
    const float* W_kj   = (const float*)d_in[9];
    const float* b_kj   = (const float*)d_in[10];
    const float* W_ji   = (const float*)d_in[11];
    const float* b_ji   = (const float*)d_in[12];
    const float* W_down = (const float*)d_in[13];
    const float* W_up   = (const float*)d_in[14];
    const float* resbW  = (const float*)d_in[15];
    const float* resbB  = (const float*)d_in[16];
    const float* W_lin  = (const float*)d_in[17];
    const float* b_lin  = (const float*)d_in[18];
    const float* resaW  = (const float*)d_in[19];
    const float* resaB  = (const float*)d_in[20];

    const int E = in_sizes[0] / HCH;
    const int T = in_sizes[3];
    float* out = (float*)d_out;

    // ws: agg f32[E*64] | wc_rbf f32[1152] | counts[E] | start[E] | bsum[512] |
    //     trip[T] | pB u16[T*8] | x64b u16[E*64] | Wt u16[WT_TOTAL]
    float* agg    = (float*)d_ws;
    float* wc_rbf = agg + (size_t)E * ICH;
    int*   counts = (int*)(wc_rbf + NRAD * HCH);
    int*   start  = counts + E;
    int*   bsum   = start + E;
    int*   trip   = bsum + 512;
    unsigned short* pB   = (unsigned short*)(trip + T);
    unsigned short* x64b = pB + (size_t)T * 8;
    unsigned short* Wt   = x64b + (size_t)E * ICH;

    const unsigned short* Wt_kj   = Wt;
    const unsigned short* Wt_ji   = Wt + 1 * WSEG;
    const unsigned short* Wt_lin  = Wt + 2 * WSEG;
    const unsigned short* Wt_rb0  = Wt + 3 * WSEG;   // W0, W1 at +WSEG
    const unsigned short* Wt_ra   = Wt + 5 * WSEG;   // ra0_0, ra0_1, ra1_0, ra1_1
    const unsigned short* Wt_down = Wt + WT_DOWN;
    const unsigned short* Wt_up   = Wt + WT_UP;

    const int gb64 = (E + 63) / 64;
    const int gt = (T + 255) / 256;
    const int gscan = (E + 1023) / 1024;

    wc_k<<<(NRAD * HCH + NT - 1) / NT, NT, 0, stream>>>(W_rbf1, W_rbf2, wc_rbf);
    prep_k<<<(WT_TOTAL + NT - 1) / NT, NT, 0, stream>>>(W_kj, W_ji, W_lin, resbW, resaW,
                                                        W_down, W_up, Wt);

    // CSR build
    hipMemsetAsync(counts, 0, (size_t)E * sizeof(int), stream);
    pcount_k<<<gt, 256, 0, stream>>>(sbf, idx_ji, W_sbf1, pB, counts, T);
    psum1_k<<<gscan, 256, 0, stream>>>(counts, bsum, E);
    psum2_k<<<1, 512, 0, stream>>>(bsum, gscan);
    psum3_k<<<gscan, 256, 0, stream>>>(counts, bsum, start, E);
    fill_k<<<gt, 256, 0, stream>>>(idx_ji, start, trip, T);

    // x -> x64b (bf16)
    fused12_k<<<gb64, NT, 0, stream>>>(x, Wt_kj, b_kj, rbf, wc_rbf, Wt_down, x64b, E);
    // agg = segment_sum(x64b[idx_kj] * (p@W_sbf2), idx_ji)
    gather_k<<<(E + 3) / 4, 256, 0, stream>>>(trip, idx_kj, pB, x64b, start, counts, W_sbf2, agg, E);
    // fused tail: combine + res_b0 + lin + res_a0 + res_a1
    tail_k<<<gb64, NT, 0, stream>>>(x, agg, Wt_ji, b_ji, Wt_up, Wt_rb0, resbB,
                                    Wt_lin, b_lin, Wt_ra, resaB, out, E);
}

// Round 5
// 4150.611 us; speedup vs baseline: 1.0738x; 1.0738x over previous
//
#include <hip/hip_runtime.h>
#include <cstdint>
#include <cstddef>

#define HCH 192
#define ICH 64
#define NRAD 6
#define SBFD 42

constexpr int NT = 256;

using bfrag = __attribute__((ext_vector_type(8))) short;  // 8 bf16 (4 VGPRs)
using f32x4 = __attribute__((ext_vector_type(4))) float;

#define MFMA16(a, b, c) __builtin_amdgcn_mfma_f32_16x16x32_bf16(a, b, c, 0, 0, 0)

__device__ __forceinline__ float silu_f(float v) {
    return v / (1.0f + __expf(-v));
}

__device__ __forceinline__ unsigned short f2bf(float x) {
    union { float f; unsigned u; } v; v.f = x;
    return (unsigned short)((v.u + 0x7FFFu + ((v.u >> 16) & 1u)) >> 16);
}

__device__ __forceinline__ float bf2f(unsigned short u) {
    union { unsigned u; float f; } v; v.u = ((unsigned)u) << 16;
    return v.f;
}

__device__ __forceinline__ bfrag pack8(float4 a, float4 b) {
    bfrag r;
    r[0] = (short)f2bf(a.x); r[1] = (short)f2bf(a.y);
    r[2] = (short)f2bf(a.z); r[3] = (short)f2bf(a.w);
    r[4] = (short)f2bf(b.x); r[5] = (short)f2bf(b.y);
    r[6] = (short)f2bf(b.z); r[7] = (short)f2bf(b.w);
    return r;
}

// ---------------- weight prep: fp32 [K][N] -> bf16 transposed [N][K] ----------------
#define WSEG 36864
#define WT_DOWN (9 * WSEG)
#define WT_UP   (9 * WSEG + 12288)
#define WT_TOTAL (9 * WSEG + 2 * 12288)

__global__ __launch_bounds__(NT) void prep_k(
    const float* __restrict__ W_kj, const float* __restrict__ W_ji,
    const float* __restrict__ W_lin, const float* __restrict__ resbW,
    const float* __restrict__ resaW, const float* __restrict__ W_down,
    const float* __restrict__ W_up, unsigned short* __restrict__ Wt)
{
    int i = blockIdx.x * NT + threadIdx.x;
    if (i < 9 * WSEG) {
        int seg = i / WSEG, r = i % WSEG;
        int k = r / HCH, n = r % HCH;
        const float* src =
            seg == 0 ? W_kj : seg == 1 ? W_ji : seg == 2 ? W_lin :
            seg <= 4 ? resbW + (seg - 3) * WSEG : resaW + (seg - 5) * WSEG;
        Wt[seg * WSEG + n * HCH + k] = f2bf(src[r]);
    } else if (i < WT_DOWN + 12288) {
        int r = i - WT_DOWN;
        int k = r / ICH, n = r % ICH;           // W_down [192][64]
        Wt[WT_DOWN + n * HCH + k] = f2bf(W_down[r]);
    } else if (i < WT_TOTAL) {
        int r = i - WT_UP;
        int k = r / HCH, n = r % HCH;           // W_up [64][192]
        Wt[WT_UP + n * ICH + k] = f2bf(W_up[r]);
    }
}

// wc_rbf[6,192] = W_rbf1[6,8] @ W_rbf2[8,192]  (kept fp32)
__global__ void wc_k(const float* __restrict__ W_rbf1, const float* __restrict__ W_rbf2,
                     float* __restrict__ wc)
{
    int tid = blockIdx.x * blockDim.x + threadIdx.x;
    if (tid < NRAD * HCH) {
        int r = tid / HCH, c = tid % HCH;
        float a = 0.f;
        #pragma unroll
        for (int b = 0; b < 8; ++b) a += W_rbf1[r * 8 + b] * W_rbf2[b * HCH + c];
        wc[tid] = a;
    }
}

// ---------------- head: x -> x64b (bf16) : W_kj + rbf modulate + W_down ----------------
__global__ __launch_bounds__(NT) void fused12_k(
    const float* __restrict__ x, const unsigned short* __restrict__ Wt_kj,
    const float* __restrict__ b_kj, const float* __restrict__ rbf,
    const float* __restrict__ wc, const unsigned short* __restrict__ Wt_down,
    unsigned short* __restrict__ x64b, int E)
{
    __shared__ unsigned short u_s[64][200];
    __shared__ float wc_s[NRAD * HCH];
    const int tid = threadIdx.x;
    const int lane = tid & 63, w = tid >> 6;
    const int row0 = blockIdx.x * 64;
    const int lr = lane & 15, lq = lane >> 4;
    const int kq = lq * 8;

    for (int i = tid; i < NRAD * HCH; i += NT) wc_s[i] = wc[i];

    const int ra = row0 + w * 16 + lr;
    const bool rav = ra < E;

    f32x4 acc[12];
    #pragma unroll
    for (int t = 0; t < 12; ++t) acc[t] = (f32x4){0.f, 0.f, 0.f, 0.f};

    #pragma unroll
    for (int ks = 0; ks < 6; ++ks) {
        const int k0 = ks * 32;
        float4 a0 = make_float4(0,0,0,0), a1 = make_float4(0,0,0,0);
        if (rav) {
            a0 = *(const float4*)(x + (size_t)ra * HCH + k0 + kq);
            a1 = *(const float4*)(x + (size_t)ra * HCH + k0 + kq + 4);
        }
        bfrag a = pack8(a0, a1);
        #pragma unroll
        for (int t = 0; t < 12; ++t) {
            bfrag b = *(const bfrag*)(Wt_kj + (size_t)(t * 16 + lr) * HCH + k0 + kq);
            acc[t] = MFMA16(a, b, acc[t]);
        }
    }
    __syncthreads();   // wc_s ready
    #pragma unroll
    for (int r = 0; r < 4; ++r) {
        int rloc = lq * 4 + r;
        int grow = row0 + w * 16 + rloc;
        float rb[NRAD];
        #pragma unroll
        for (int q = 0; q < NRAD; ++q) rb[q] = 0.f;
        if (grow < E) {
            #pragma unroll
            for (int q = 0; q < NRAD; ++q) rb[q] = rbf[(size_t)grow * NRAD + q];
        }
        #pragma unroll
        for (int t = 0; t < 12; ++t) {
            int col = t * 16 + lr;
            float sv = silu_f(acc[t][r] + b_kj[col]);
            float rh = 0.f;
            #pragma unroll
            for (int q = 0; q < NRAD; ++q) rh += rb[q] * wc_s[q * HCH + col];
            u_s[w * 16 + rloc][col] = f2bf(sv * rh);
        }
    }
    __syncthreads();   // u_s visible (cross-lane)

    f32x4 acc2[4];
    #pragma unroll
    for (int t = 0; t < 4; ++t) acc2[t] = (f32x4){0.f, 0.f, 0.f, 0.f};
    #pragma unroll
    for (int ks = 0; ks < 6; ++ks) {
        const int k0 = ks * 32;
        bfrag a = *(const bfrag*)&u_s[w * 16 + lr][k0 + kq];
        #pragma unroll
        for (int t = 0; t < 4; ++t) {
            bfrag b = *(const bfrag*)(Wt_down + (size_t)(t * 16 + lr) * HCH + k0 + kq);
            acc2[t] = MFMA16(a, b, acc2[t]);
        }
    }
    #pragma unroll
    for (int r = 0; r < 4; ++r) {
        int grow = row0 + w * 16 + lq * 4 + r;
        if (grow >= E) continue;
        #pragma unroll
        for (int t = 0; t < 4; ++t)
            x64b[(size_t)grow * ICH + t * 16 + lr] = f2bf(silu_f(acc2[t][r]));
    }
}

// ---------------- tail kernels (round-3 proven versions, de-fused) ----------------

// out = silu(x@W_ji + b_ji) + silu(agg@W_up)
__global__ __launch_bounds__(NT) void combine_k(
    const float* __restrict__ x, const unsigned short* __restrict__ Wt_ji,
    const float* __restrict__ b_ji, const float* __restrict__ agg,
    const unsigned short* __restrict__ Wt_up, float* __restrict__ out, int E)
{
    const int tid = threadIdx.x;
    const int lane = tid & 63, w = tid >> 6;
    const int row0 = blockIdx.x * 64;
    const int lr = lane & 15, lq = lane >> 4;
    const int kq = lq * 8;
    const int ra = row0 + w * 16 + lr;
    const bool rav = ra < E;

    f32x4 acc[12], acc2[12];
    #pragma unroll
    for (int t = 0; t < 12; ++t) {
        acc[t] = (f32x4){0.f, 0.f, 0.f, 0.f};
        acc2[t] = (f32x4){0.f, 0.f, 0.f, 0.f};
    }

    #pragma unroll
    for (int ks = 0; ks < 6; ++ks) {
        const int k0 = ks * 32;
        float4 a0 = make_float4(0,0,0,0), a1 = make_float4(0,0,0,0);
        if (rav) {
            a0 = *(const float4*)(x + (size_t)ra * HCH + k0 + kq);
            a1 = *(const float4*)(x + (size_t)ra * HCH + k0 + kq + 4);
        }
        bfrag a = pack8(a0, a1);
        #pragma unroll
        for (int t = 0; t < 12; ++t) {
            bfrag b = *(const bfrag*)(Wt_ji + (size_t)(t * 16 + lr) * HCH + k0 + kq);
            acc[t] = MFMA16(a, b, acc[t]);
        }
    }
    #pragma unroll
    for (int ks = 0; ks < 2; ++ks) {
        const int k0 = ks * 32;
        float4 a0 = make_float4(0,0,0,0), a1 = make_float4(0,0,0,0);
        if (rav) {
            a0 = *(const float4*)(agg + (size_t)ra * ICH + k0 + kq);
            a1 = *(const float4*)(agg + (size_t)ra * ICH + k0 + kq + 4);
        }
        bfrag a = pack8(a0, a1);
        #pragma unroll
        for (int t = 0; t < 12; ++t) {
            bfrag b = *(const bfrag*)(Wt_up + (size_t)(t * 16 + lr) * ICH + k0 + kq);
            acc2[t] = MFMA16(a, b, acc2[t]);
        }
    }
    #pragma unroll
    for (int r = 0; r < 4; ++r) {
        int grow = row0 + w * 16 + lq * 4 + r;
        if (grow >= E) continue;
        #pragma unroll
        for (int t = 0; t < 12; ++t) {
            int col = t * 16 + lr;
            out[(size_t)grow * HCH + col] =
                silu_f(acc[t][r] + b_ji[col]) + silu_f(acc2[t][r]);
        }
    }
}

// residual layer, in-place: h = h + silu(silu(h@W0+b0)@W1 + b1)
__global__ __launch_bounds__(NT) void res_k(
    float* __restrict__ h, const unsigned short* __restrict__ Wt0,
    const unsigned short* __restrict__ Wt1, const float* __restrict__ b0,
    const float* __restrict__ b1, int E)
{
    __shared__ float h_s[64][196];
    __shared__ unsigned short t_s[64][200];
    const int tid = threadIdx.x;
    const int lane = tid & 63, w = tid >> 6;
    const int row0 = blockIdx.x * 64;
    const int lr = lane & 15, lq = lane >> 4;
    const int kq = lq * 8;

    for (int i = tid; i < 64 * 48; i += NT) {
        int r = i / 48, c4 = (i % 48) * 4;
        int gr = row0 + r;
        float4 v = make_float4(0,0,0,0);
        if (gr < E) v = *(const float4*)(h + (size_t)gr * HCH + c4);
        *(float4*)&h_s[r][c4] = v;
    }
    __syncthreads();

    f32x4 acc[12];
    #pragma unroll
    for (int t = 0; t < 12; ++t) acc[t] = (f32x4){0.f, 0.f, 0.f, 0.f};

    #pragma unroll
    for (int ks = 0; ks < 6; ++ks) {
        const int k0 = ks * 32;
        float4 a0 = *(const float4*)&h_s[w * 16 + lr][k0 + kq];
        float4 a1 = *(const float4*)&h_s[w * 16 + lr][k0 + kq + 4];
        bfrag a = pack8(a0, a1);
        #pragma unroll
        for (int t = 0; t < 12; ++t) {
            bfrag b = *(const bfrag*)(Wt0 + (size_t)(t * 16 + lr) * HCH + k0 + kq);
            acc[t] = MFMA16(a, b, acc[t]);
        }
    }
    #pragma unroll
    for (int r = 0; r < 4; ++r) {
        int rloc = lq * 4 + r;
        #pragma unroll
        for (int t = 0; t < 12; ++t) {
            int col = t * 16 + lr;
            t_s[w * 16 + rloc][col] = f2bf(silu_f(acc[t][r] + b0[col]));
        }
    }
    __syncthreads();   // t_s visible (cross-lane)

    #pragma unroll
    for (int t = 0; t < 12; ++t) acc[t] = (f32x4){0.f, 0.f, 0.f, 0.f};
    #pragma unroll
    for (int ks = 0; ks < 6; ++ks) {
        const int k0 = ks * 32;
        bfrag a = *(const bfrag*)&t_s[w * 16 + lr][k0 + kq];
        #pragma unroll
        for (int t = 0; t < 12; ++t) {
            bfrag b = *(const bfrag*)(Wt1 + (size_t)(t * 16 + lr) * HCH + k0 + kq);
            acc[t] = MFMA16(a, b, acc[t]);
        }
    }
    #pragma unroll
    for (int r = 0; r < 4; ++r) {
        int rloc = lq * 4 + r;
        int grow = row0 + w * 16 + rloc;
        if (grow >= E) continue;
        #pragma unroll
        for (int t = 0; t < 12; ++t) {
            int col = t * 16 + lr;
            h[(size_t)grow * HCH + col] =
                h_s[rloc + w * 16][col] + silu_f(acc[t][r] + b1[col]);
        }
    }
}

// h = silu(h@W_lin + b_lin) + x, in-place
__global__ __launch_bounds__(NT) void lin_k(
    float* __restrict__ h, const unsigned short* __restrict__ Wt_lin,
    const float* __restrict__ b_lin, const float* __restrict__ x, int E)
{
    const int tid = threadIdx.x;
    const int lane = tid & 63, w = tid >> 6;
    const int row0 = blockIdx.x * 64;
    const int lr = lane & 15, lq = lane >> 4;
    const int kq = lq * 8;
    const int ra = row0 + w * 16 + lr;
    const bool rav = ra < E;

    f32x4 acc[12];
    #pragma unroll
    for (int t = 0; t < 12; ++t) acc[t] = (f32x4){0.f, 0.f, 0.f, 0.f};

    #pragma unroll
    for (int ks = 0; ks < 6; ++ks) {
        const int k0 = ks * 32;
        float4 a0 = make_float4(0,0,0,0), a1 = make_float4(0,0,0,0);
        if (rav) {
            a0 = *(const float4*)(h + (size_t)ra * HCH + k0 + kq);
            a1 = *(const float4*)(h + (size_t)ra * HCH + k0 + kq + 4);
        }
        bfrag a = pack8(a0, a1);
        #pragma unroll
        for (int t = 0; t < 12; ++t) {
            bfrag b = *(const bfrag*)(Wt_lin + (size_t)(t * 16 + lr) * HCH + k0 + kq);
            acc[t] = MFMA16(a, b, acc[t]);
        }
    }
    #pragma unroll
    for (int r = 0; r < 4; ++r) {
        int grow = row0 + w * 16 + lq * 4 + r;
        if (grow >= E) continue;
        #pragma unroll
        for (int t = 0; t < 12; ++t) {
            int col = t * 16 + lr;
            h[(size_t)grow * HCH + col] =
                silu_f(acc[t][r] + b_lin[col]) + x[(size_t)grow * HCH + col];
        }
    }
}

// ---------------- CSR scatter->gather pipeline (bf16 p / x64) ----------------
__global__ __launch_bounds__(256) void pcount_k(
    const float* __restrict__ sbf, const int* __restrict__ idx_ji,
    const float* __restrict__ w1, unsigned short* __restrict__ pB,
    int* __restrict__ counts, int T)
{
    int t = blockIdx.x * 256 + threadIdx.x;
    if (t >= T) return;
    const float* sp = sbf + (size_t)t * SBFD;
    float acc[8];
    #pragma unroll
    for (int b = 0; b < 8; ++b) acc[b] = 0.f;
    #pragma unroll
    for (int r = 0; r < SBFD; r += 2) {
        float2 v = *(const float2*)(sp + r);
        #pragma unroll
        for (int b = 0; b < 8; ++b)
            acc[b] += v.x * w1[r * 8 + b] + v.y * w1[(r + 1) * 8 + b];
    }
    uint4 pk;
    pk.x = (unsigned)f2bf(acc[0]) | ((unsigned)f2bf(acc[1]) << 16);
    pk.y = (unsigned)f2bf(acc[2]) | ((unsigned)f2bf(acc[3]) << 16);
    pk.z = (unsigned)f2bf(acc[4]) | ((unsigned)f2bf(acc[5]) << 16);
    pk.w = (unsigned)f2bf(acc[6]) | ((unsigned)f2bf(acc[7]) << 16);
    *(uint4*)(pB + (size_t)t * 8) = pk;
    atomicAdd(&counts[idx_ji[t]], 1);
}

__global__ __launch_bounds__(256) void psum1_k(const int* __restrict__ counts,
                                               int* __restrict__ bsum, int E) {
    __shared__ int s[256];
    int base = blockIdx.x * 1024;
    int tid = threadIdx.x;
    int sum = 0;
    #pragma unroll
    for (int j = 0; j < 4; ++j) { int i = base + j * 256 + tid; if (i < E) sum += counts[i]; }
    s[tid] = sum; __syncthreads();
    for (int off = 128; off > 0; off >>= 1) {
        if (tid < off) s[tid] += s[tid + off];
        __syncthreads();
    }
    if (tid == 0) bsum[blockIdx.x] = s[0];
}

__global__ __launch_bounds__(512) void psum2_k(int* bsum, int G) {
    __shared__ int s[512];
    int tid = threadIdx.x;
    s[tid] = (tid < G) ? bsum[tid] : 0;
    for (int off = 1; off < 512; off <<= 1) {
        __syncthreads();
        int v = (tid >= off) ? s[tid - off] : 0;
        __syncthreads();
        s[tid] += v;
    }
    __syncthreads();
    if (tid < G) bsum[tid] = (tid == 0) ? 0 : s[tid - 1];
}

__global__ __launch_bounds__(256) void psum3_k(const int* __restrict__ counts,
                                               const int* __restrict__ bsum,
                                               int* __restrict__ start, int E) {
    __shared__ int s[256];
    int tid = threadIdx.x;
    int base = blockIdx.x * 1024 + tid * 4;
    int v[4]; int loc = 0;
    #pragma unroll
    for (int j = 0; j < 4; ++j) { v[j] = (base + j < E) ? counts[base + j] : 0; loc += v[j]; }
    s[tid] = loc;
    for (int off = 1; off < 256; off <<= 1) {
        __syncthreads();
        int t2 = (tid >= off) ? s[tid - off] : 0;
        __syncthreads();
        s[tid] += t2;
    }
    __syncthreads();
    int run = bsum[blockIdx.x] + s[tid] - loc;
    #pragma unroll
    for (int j = 0; j < 4; ++j) { if (base + j < E) start[base + j] = run; run += v[j]; }
}

__global__ __launch_bounds__(256) void fill_k(const int* __restrict__ idx_ji,
                                              int* __restrict__ start,
                                              int* __restrict__ trip, int T) {
    int t = blockIdx.x * 256 + threadIdx.x;
    if (t >= T) return;
    int pos = atomicAdd(&start[idx_ji[t]], 1);
    trip[pos] = t;
}

__global__ __launch_bounds__(256) void gather_k(
    const int* __restrict__ trip, const int* __restrict__ idx_kj,
    const unsigned short* __restrict__ pB, const unsigned short* __restrict__ x64b,
    const int* __restrict__ start, const int* __restrict__ counts,
    const float* __restrict__ w2, float* __restrict__ agg, int E)
{
    __shared__ float w2s[8 * 64];
    int tid = threadIdx.x;
    for (int i = tid; i < 8 * 64; i += 256) w2s[i] = w2[i];
    __syncthreads();

    int wave = (blockIdx.x * 256 + tid) >> 6;
    int lane = tid & 63;
    if (wave >= E) return;

    int n = counts[wave];
    int end = start[wave];
    int begin = end - n;

    float acc = 0.f;
    for (int i = begin; i < end; ++i) {
        int t = trip[i];
        int kj = idx_kj[t];
        float p8 = bf2f(pB[(size_t)t * 8 + (lane & 7)]);
        float xv = bf2f(x64b[(size_t)kj * ICH + lane]);
        float sc = 0.f;
        #pragma unroll
        for (int b = 0; b < 8; ++b)
            sc += __shfl(p8, b, 64) * w2s[b * 64 + lane];
        acc += sc * xv;
    }
    agg[(size_t)wave * ICH + lane] = acc;
}

extern "C" void kernel_launch(void* const* d_in, const int* in_sizes, int n_in,
                              void* d_out, int out_size, void* d_ws, size_t ws_size,
                              hipStream_t stream) {
    const float* x      = (const float*)d_in[0];
    const float* rbf    = (const float*)d_in[1];
    const float* sbf    = (const float*)d_in[2];
    const int*   idx_kj = (const int*)d_in[3];
    const int*   idx_ji = (const int*)d_in[4];
    const float* W_rbf1 = (const float*)d_in[5];
    const float* W_rbf2 = (const float*)d_in[6];
    const float* W_sbf1 = (const float*)d_in[7];
    const float* W_sbf2 = (const float*)d_in[8];
    const float* W_kj   = (const float*)d_in[9];
    const float* b_kj   = (const float*)d_in[10];
    const float* W_ji   = (const float*)d_in[11];
    const float* b_ji   = (const float*)d_in[12];
    const float* W_down = (const float*)d_in[13];
    const float* W_up   = (const float*)d_in[14];
    const float* resbW  = (const float*)d_in[15];
    const float* resbB  = (const float*)d_in[16];
    const float* W_lin  = (const float*)d_in[17];
    const float* b_lin  = (const float*)d_in[18];
    const float* resaW  = (const float*)d_in[19];
    const float* resaB  = (const float*)d_in[20];

    const int E = in_sizes[0] / HCH;
    const int T = in_sizes[3];
    float* out = (float*)d_out;

    // ws: agg f32[E*64] | wc_rbf f32[1152] | counts[E] | start[E] | bsum[512] |
    //     trip[T] | pB u16[T*8] | x64b u16[E*64] | Wt u16[WT_TOTAL]
    float* agg    = (float*)d_ws;
    float* wc_rbf = agg + (size_t)E * ICH;
    int*   counts = (int*)(wc_rbf + NRAD * HCH);
    int*   start  = counts + E;
    int*   bsum   = start + E;
    int*   trip   = bsum + 512;
    unsigned short* pB   = (unsigned short*)(trip + T);
    unsigned short* x64b = pB + (size_t)T * 8;
    unsigned short* Wt   = x64b + (size_t)E * ICH;

    const unsigned short* Wt_kj   = Wt;
    const unsigned short* Wt_ji   = Wt + 1 * WSEG;
    const unsigned short* Wt_lin  = Wt + 2 * WSEG;
    const unsigned short* Wt_rb0  = Wt + 3 * WSEG;   // W0, W1 at +WSEG
    const unsigned short* Wt_ra   = Wt + 5 * WSEG;   // ra0_0, ra0_1, ra1_0, ra1_1
    const unsigned short* Wt_down = Wt + WT_DOWN;
    const unsigned short* Wt_up   = Wt + WT_UP;

    const int gb64 = (E + 63) / 64;
    const int gt = (T + 255) / 256;
    const int gscan = (E + 1023) / 1024;

    wc_k<<<(NRAD * HCH + NT - 1) / NT, NT, 0, stream>>>(W_rbf1, W_rbf2, wc_rbf);
    prep_k<<<(WT_TOTAL + NT - 1) / NT, NT, 0, stream>>>(W_kj, W_ji, W_lin, resbW, resaW,
                                                        W_down, W_up, Wt);

    // CSR build
    hipMemsetAsync(counts, 0, (size_t)E * sizeof(int), stream);
    pcount_k<<<gt, 256, 0, stream>>>(sbf, idx_ji, W_sbf1, pB, counts, T);
    psum1_k<<<gscan, 256, 0, stream>>>(counts, bsum, E);
    psum2_k<<<1, 512, 0, stream>>>(bsum, gscan);
    psum3_k<<<gscan, 256, 0, stream>>>(counts, bsum, start, E);
    fill_k<<<gt, 256, 0, stream>>>(idx_ji, start, trip, T);

    // x -> x64b (bf16)
    fused12_k<<<gb64, NT, 0, stream>>>(x, Wt_kj, b_kj, rbf, wc_rbf, Wt_down, x64b, E);
    // agg = segment_sum(x64b[idx_kj] * (p@W_sbf2), idx_ji)
    gather_k<<<(E + 3) / 4, 256, 0, stream>>>(trip, idx_kj, pB, x64b, start, counts, W_sbf2, agg, E);
    // h = silu(x@W_ji+b) + silu(agg@W_up)
    combine_k<<<gb64, NT, 0, stream>>>(x, Wt_ji, b_ji, agg, Wt_up, out, E);
    // res_before
    res_k<<<gb64, NT, 0, stream>>>(out, Wt_rb0, Wt_rb0 + WSEG, resbB, resbB + HCH, E);
    // h = silu(h@W_lin + b_lin) + x
    lin_k<<<gb64, NT, 0, stream>>>(out, Wt_lin, b_lin, x, E);
    // res_after x2
    res_k<<<gb64, NT, 0, stream>>>(out, Wt_ra, Wt_ra + WSEG, resaB, resaB + HCH, E);
    res_k<<<gb64, NT, 0, stream>>>(out, Wt_ra + 2 * WSEG, Wt_ra + 3 * WSEG,
                                   resaB + 2 * HCH, resaB + 3 * HCH, E);
}

// Round 6
// 3443.142 us; speedup vs baseline: 1.2944x; 1.2055x over previous
//
#include <hip/hip_runtime.h>
#include <cstdint>
#include <cstddef>

#define HCH 192
#define ICH 64
#define NRAD 6
#define SBFD 42

constexpr int NT = 256;

using bfrag = __attribute__((ext_vector_type(8))) short;  // 8 bf16 (4 VGPRs)
using f32x4 = __attribute__((ext_vector_type(4))) float;

#define MFMA16(a, b, c) __builtin_amdgcn_mfma_f32_16x16x32_bf16(a, b, c, 0, 0, 0)

__device__ __forceinline__ float silu_f(float v) {
    return v / (1.0f + __expf(-v));
}

__device__ __forceinline__ unsigned short f2bf(float x) {
    union { float f; unsigned u; } v; v.f = x;
    return (unsigned short)((v.u + 0x7FFFu + ((v.u >> 16) & 1u)) >> 16);
}

__device__ __forceinline__ float bf2f(unsigned short u) {
    union { unsigned u; float f; } v; v.u = ((unsigned)u) << 16;
    return v.f;
}

__device__ __forceinline__ float lo16(unsigned u) {
    union { unsigned x; float f; } v; v.x = u << 16; return v.f;
}
__device__ __forceinline__ float hi16(unsigned u) {
    union { unsigned x; float f; } v; v.x = u & 0xffff0000u; return v.f;
}

__device__ __forceinline__ bfrag pack8(float4 a, float4 b) {
    bfrag r;
    r[0] = (short)f2bf(a.x); r[1] = (short)f2bf(a.y);
    r[2] = (short)f2bf(a.z); r[3] = (short)f2bf(a.w);
    r[4] = (short)f2bf(b.x); r[5] = (short)f2bf(b.y);
    r[6] = (short)f2bf(b.z); r[7] = (short)f2bf(b.w);
    return r;
}

__device__ __forceinline__ bfrag bzero() {
    bfrag r;
    #pragma unroll
    for (int i = 0; i < 8; ++i) r[i] = 0;
    return r;
}

// ---------------- weight prep: fp32 [K][N] -> bf16 transposed [N][K] ----------------
#define WSEG 36864
#define WT_DOWN (9 * WSEG)
#define WT_UP   (9 * WSEG + 12288)
#define WT_TOTAL (9 * WSEG + 2 * 12288)

__global__ __launch_bounds__(NT) void prep_k(
    const float* __restrict__ W_kj, const float* __restrict__ W_ji,
    const float* __restrict__ W_lin, const float* __restrict__ resbW,
    const float* __restrict__ resaW, const float* __restrict__ W_down,
    const float* __restrict__ W_up, unsigned short* __restrict__ Wt)
{
    int i = blockIdx.x * NT + threadIdx.x;
    if (i < 9 * WSEG) {
        int seg = i / WSEG, r = i % WSEG;
        int k = r / HCH, n = r % HCH;
        const float* src =
            seg == 0 ? W_kj : seg == 1 ? W_ji : seg == 2 ? W_lin :
            seg <= 4 ? resbW + (seg - 3) * WSEG : resaW + (seg - 5) * WSEG;
        Wt[seg * WSEG + n * HCH + k] = f2bf(src[r]);
    } else if (i < WT_DOWN + 12288) {
        int r = i - WT_DOWN;
        int k = r / ICH, n = r % ICH;           // W_down [192][64]
        Wt[WT_DOWN + n * HCH + k] = f2bf(W_down[r]);
    } else if (i < WT_TOTAL) {
        int r = i - WT_UP;
        int k = r / HCH, n = r % HCH;           // W_up [64][192]
        Wt[WT_UP + n * ICH + k] = f2bf(W_up[r]);
    }
}

// wc_rbf[6,192] = W_rbf1[6,8] @ W_rbf2[8,192]  (kept fp32)
__global__ void wc_k(const float* __restrict__ W_rbf1, const float* __restrict__ W_rbf2,
                     float* __restrict__ wc)
{
    int tid = blockIdx.x * blockDim.x + threadIdx.x;
    if (tid < NRAD * HCH) {
        int r = tid / HCH, c = tid % HCH;
        float a = 0.f;
        #pragma unroll
        for (int b = 0; b < 8; ++b) a += W_rbf1[r * 8 + b] * W_rbf2[b * HCH + c];
        wc[tid] = a;
    }
}

// ---------------- head: x -> x64b (bf16) : W_kj + rbf modulate + W_down ----------------
__global__ __launch_bounds__(NT) void fused12_k(
    const float* __restrict__ x, const unsigned short* __restrict__ Wt_kj,
    const float* __restrict__ b_kj, const float* __restrict__ rbf,
    const float* __restrict__ wc, const unsigned short* __restrict__ Wt_down,
    unsigned short* __restrict__ x64b, int E)
{
    __shared__ unsigned short u_s[64][200];
    __shared__ float wc_s[NRAD * HCH];
    const int tid = threadIdx.x;
    const int lane = tid & 63, w = tid >> 6;
    const int row0 = blockIdx.x * 64;
    const int lr = lane & 15, lq = lane >> 4;
    const int kq = lq * 8;

    for (int i = tid; i < NRAD * HCH; i += NT) wc_s[i] = wc[i];

    const int ra = row0 + w * 16 + lr;
    const bool rav = ra < E;

    f32x4 acc[12];
    #pragma unroll
    for (int t = 0; t < 12; ++t) acc[t] = (f32x4){0.f, 0.f, 0.f, 0.f};

    #pragma unroll
    for (int ks = 0; ks < 6; ++ks) {
        const int k0 = ks * 32;
        float4 a0 = make_float4(0,0,0,0), a1 = make_float4(0,0,0,0);
        if (rav) {
            a0 = *(const float4*)(x + (size_t)ra * HCH + k0 + kq);
            a1 = *(const float4*)(x + (size_t)ra * HCH + k0 + kq + 4);
        }
        bfrag a = pack8(a0, a1);
        #pragma unroll
        for (int t = 0; t < 12; ++t) {
            bfrag b = *(const bfrag*)(Wt_kj + (size_t)(t * 16 + lr) * HCH + k0 + kq);
            acc[t] = MFMA16(a, b, acc[t]);
        }
    }
    __syncthreads();   // wc_s ready
    #pragma unroll
    for (int r = 0; r < 4; ++r) {
        int rloc = lq * 4 + r;
        int grow = row0 + w * 16 + rloc;
        float rb[NRAD];
        #pragma unroll
        for (int q = 0; q < NRAD; ++q) rb[q] = 0.f;
        if (grow < E) {
            #pragma unroll
            for (int q = 0; q < NRAD; ++q) rb[q] = rbf[(size_t)grow * NRAD + q];
        }
        #pragma unroll
        for (int t = 0; t < 12; ++t) {
            int col = t * 16 + lr;
            float sv = silu_f(acc[t][r] + b_kj[col]);
            float rh = 0.f;
            #pragma unroll
            for (int q = 0; q < NRAD; ++q) rh += rb[q] * wc_s[q * HCH + col];
            u_s[w * 16 + rloc][col] = f2bf(sv * rh);
        }
    }
    __syncthreads();   // u_s visible (cross-lane)

    f32x4 acc2[4];
    #pragma unroll
    for (int t = 0; t < 4; ++t) acc2[t] = (f32x4){0.f, 0.f, 0.f, 0.f};
    #pragma unroll
    for (int ks = 0; ks < 6; ++ks) {
        const int k0 = ks * 32;
        bfrag a = *(const bfrag*)&u_s[w * 16 + lr][k0 + kq];
        #pragma unroll
        for (int t = 0; t < 4; ++t) {
            bfrag b = *(const bfrag*)(Wt_down + (size_t)(t * 16 + lr) * HCH + k0 + kq);
            acc2[t] = MFMA16(a, b, acc2[t]);
        }
    }
    #pragma unroll
    for (int r = 0; r < 4; ++r) {
        int grow = row0 + w * 16 + lq * 4 + r;
        if (grow >= E) continue;
        #pragma unroll
        for (int t = 0; t < 4; ++t)
            x64b[(size_t)grow * ICH + t * 16 + lr] = f2bf(silu_f(acc2[t][r]));
    }
}

// ---------------- tail kernels ----------------

// out = silu(x@W_ji + b_ji) + silu(agg@W_up)   (agg read as bf16)
__global__ __launch_bounds__(NT) void combine_k(
    const float* __restrict__ x, const unsigned short* __restrict__ Wt_ji,
    const float* __restrict__ b_ji, const unsigned short* __restrict__ aggB,
    const unsigned short* __restrict__ Wt_up, float* __restrict__ out, int E)
{
    const int tid = threadIdx.x;
    const int lane = tid & 63, w = tid >> 6;
    const int row0 = blockIdx.x * 64;
    const int lr = lane & 15, lq = lane >> 4;
    const int kq = lq * 8;
    const int ra = row0 + w * 16 + lr;
    const bool rav = ra < E;

    f32x4 acc[12], acc2[12];
    #pragma unroll
    for (int t = 0; t < 12; ++t) {
        acc[t] = (f32x4){0.f, 0.f, 0.f, 0.f};
        acc2[t] = (f32x4){0.f, 0.f, 0.f, 0.f};
    }

    #pragma unroll
    for (int ks = 0; ks < 6; ++ks) {
        const int k0 = ks * 32;
        float4 a0 = make_float4(0,0,0,0), a1 = make_float4(0,0,0,0);
        if (rav) {
            a0 = *(const float4*)(x + (size_t)ra * HCH + k0 + kq);
            a1 = *(const float4*)(x + (size_t)ra * HCH + k0 + kq + 4);
        }
        bfrag a = pack8(a0, a1);
        #pragma unroll
        for (int t = 0; t < 12; ++t) {
            bfrag b = *(const bfrag*)(Wt_ji + (size_t)(t * 16 + lr) * HCH + k0 + kq);
            acc[t] = MFMA16(a, b, acc[t]);
        }
    }
    #pragma unroll
    for (int ks = 0; ks < 2; ++ks) {
        const int k0 = ks * 32;
        bfrag a = rav ? *(const bfrag*)(aggB + (size_t)ra * ICH + k0 + kq) : bzero();
        #pragma unroll
        for (int t = 0; t < 12; ++t) {
            bfrag b = *(const bfrag*)(Wt_up + (size_t)(t * 16 + lr) * ICH + k0 + kq);
            acc2[t] = MFMA16(a, b, acc2[t]);
        }
    }
    #pragma unroll
    for (int r = 0; r < 4; ++r) {
        int grow = row0 + w * 16 + lq * 4 + r;
        if (grow >= E) continue;
        #pragma unroll
        for (int t = 0; t < 12; ++t) {
            int col = t * 16 + lr;
            out[(size_t)grow * HCH + col] =
                silu_f(acc[t][r] + b_ji[col]) + silu_f(acc2[t][r]);
        }
    }
}

// residual layer, in-place, 128 rows/block (32/wave): h += silu(silu(h@W0+b0)@W1+b1)
__global__ __launch_bounds__(NT) void res_k(
    float* __restrict__ h, const unsigned short* __restrict__ Wt0,
    const unsigned short* __restrict__ Wt1, const float* __restrict__ b0,
    const float* __restrict__ b1, int E)
{
    __shared__ unsigned short t_s[128][200];
    const int tid = threadIdx.x;
    const int lane = tid & 63, w = tid >> 6;
    const int row0 = blockIdx.x * 128;
    const int wbase = w * 32;
    const int lr = lane & 15, lq = lane >> 4;
    const int kq = lq * 8;

    f32x4 acc[2][12];
    #pragma unroll
    for (int g = 0; g < 2; ++g)
        #pragma unroll
        for (int t = 0; t < 12; ++t) acc[g][t] = (f32x4){0.f, 0.f, 0.f, 0.f};

    // GEMM 1: A from global h (own rows), B shared across both row-groups
    #pragma unroll
    for (int ks = 0; ks < 6; ++ks) {
        const int k0 = ks * 32;
        bfrag afr[2];
        #pragma unroll
        for (int g = 0; g < 2; ++g) {
            int row = row0 + wbase + g * 16 + lr;
            float4 a0 = make_float4(0,0,0,0), a1 = make_float4(0,0,0,0);
            if (row < E) {
                a0 = *(const float4*)(h + (size_t)row * HCH + k0 + kq);
                a1 = *(const float4*)(h + (size_t)row * HCH + k0 + kq + 4);
            }
            afr[g] = pack8(a0, a1);
        }
        #pragma unroll
        for (int t = 0; t < 12; ++t) {
            bfrag b = *(const bfrag*)(Wt0 + (size_t)(t * 16 + lr) * HCH + k0 + kq);
            acc[0][t] = MFMA16(afr[0], b, acc[0][t]);
            acc[1][t] = MFMA16(afr[1], b, acc[1][t]);
        }
    }
    #pragma unroll
    for (int g = 0; g < 2; ++g)
        #pragma unroll
        for (int r = 0; r < 4; ++r) {
            int rloc = wbase + g * 16 + lq * 4 + r;
            #pragma unroll
            for (int t = 0; t < 12; ++t) {
                int col = t * 16 + lr;
                t_s[rloc][col] = f2bf(silu_f(acc[g][t][r] + b0[col]));
            }
        }
    __syncthreads();

    #pragma unroll
    for (int g = 0; g < 2; ++g)
        #pragma unroll
        for (int t = 0; t < 12; ++t) acc[g][t] = (f32x4){0.f, 0.f, 0.f, 0.f};

    // GEMM 2: A from t_s
    #pragma unroll
    for (int ks = 0; ks < 6; ++ks) {
        const int k0 = ks * 32;
        bfrag afr0 = *(const bfrag*)&t_s[wbase + lr][k0 + kq];
        bfrag afr1 = *(const bfrag*)&t_s[wbase + 16 + lr][k0 + kq];
        #pragma unroll
        for (int t = 0; t < 12; ++t) {
            bfrag b = *(const bfrag*)(Wt1 + (size_t)(t * 16 + lr) * HCH + k0 + kq);
            acc[0][t] = MFMA16(afr0, b, acc[0][t]);
            acc[1][t] = MFMA16(afr1, b, acc[1][t]);
        }
    }
    #pragma unroll
    for (int g = 0; g < 2; ++g)
        #pragma unroll
        for (int r = 0; r < 4; ++r) {
            int grow = row0 + wbase + g * 16 + lq * 4 + r;
            if (grow >= E) continue;
            #pragma unroll
            for (int t = 0; t < 12; ++t) {
                int col = t * 16 + lr;
                h[(size_t)grow * HCH + col] += silu_f(acc[g][t][r] + b1[col]);
            }
        }
}

// h = silu(h@W_lin + b_lin) + x, in-place, 128 rows/block (32/wave), no LDS
__global__ __launch_bounds__(NT) void lin_k(
    float* __restrict__ h, const unsigned short* __restrict__ Wt_lin,
    const float* __restrict__ b_lin, const float* __restrict__ x, int E)
{
    const int tid = threadIdx.x;
    const int lane = tid & 63, w = tid >> 6;
    const int row0 = blockIdx.x * 128;
    const int wbase = w * 32;
    const int lr = lane & 15, lq = lane >> 4;
    const int kq = lq * 8;

    f32x4 acc[2][12];
    #pragma unroll
    for (int g = 0; g < 2; ++g)
        #pragma unroll
        for (int t = 0; t < 12; ++t) acc[g][t] = (f32x4){0.f, 0.f, 0.f, 0.f};

    #pragma unroll
    for (int ks = 0; ks < 6; ++ks) {
        const int k0 = ks * 32;
        bfrag afr[2];
        #pragma unroll
        for (int g = 0; g < 2; ++g) {
            int row = row0 + wbase + g * 16 + lr;
            float4 a0 = make_float4(0,0,0,0), a1 = make_float4(0,0,0,0);
            if (row < E) {
                a0 = *(const float4*)(h + (size_t)row * HCH + k0 + kq);
                a1 = *(const float4*)(h + (size_t)row * HCH + k0 + kq + 4);
            }
            afr[g] = pack8(a0, a1);
        }
        #pragma unroll
        for (int t = 0; t < 12; ++t) {
            bfrag b = *(const bfrag*)(Wt_lin + (size_t)(t * 16 + lr) * HCH + k0 + kq);
            acc[0][t] = MFMA16(afr[0], b, acc[0][t]);
            acc[1][t] = MFMA16(afr[1], b, acc[1][t]);
        }
    }
    #pragma unroll
    for (int g = 0; g < 2; ++g)
        #pragma unroll
        for (int r = 0; r < 4; ++r) {
            int grow = row0 + wbase + g * 16 + lq * 4 + r;
            if (grow >= E) continue;
            #pragma unroll
            for (int t = 0; t < 12; ++t) {
                int col = t * 16 + lr;
                h[(size_t)grow * HCH + col] =
                    silu_f(acc[g][t][r] + b_lin[col]) + x[(size_t)grow * HCH + col];
            }
        }
}

// ---------------- CSR scatter->gather pipeline ----------------
__global__ __launch_bounds__(256) void pcount_k(
    const float* __restrict__ sbf, const int* __restrict__ idx_ji,
    const float* __restrict__ w1, unsigned short* __restrict__ pB,
    int* __restrict__ counts, int T)
{
    int t = blockIdx.x * 256 + threadIdx.x;
    if (t >= T) return;
    const float* sp = sbf + (size_t)t * SBFD;
    float acc[8];
    #pragma unroll
    for (int b = 0; b < 8; ++b) acc[b] = 0.f;
    #pragma unroll
    for (int r = 0; r < SBFD; r += 2) {
        float2 v = *(const float2*)(sp + r);
        #pragma unroll
        for (int b = 0; b < 8; ++b)
            acc[b] += v.x * w1[r * 8 + b] + v.y * w1[(r + 1) * 8 + b];
    }
    uint4 pk;
    pk.x = (unsigned)f2bf(acc[0]) | ((unsigned)f2bf(acc[1]) << 16);
    pk.y = (unsigned)f2bf(acc[2]) | ((unsigned)f2bf(acc[3]) << 16);
    pk.z = (unsigned)f2bf(acc[4]) | ((unsigned)f2bf(acc[5]) << 16);
    pk.w = (unsigned)f2bf(acc[6]) | ((unsigned)f2bf(acc[7]) << 16);
    *(uint4*)(pB + (size_t)t * 8) = pk;
    atomicAdd(&counts[idx_ji[t]], 1);
}

__global__ __launch_bounds__(256) void psum1_k(const int* __restrict__ counts,
                                               int* __restrict__ bsum, int E) {
    __shared__ int s[256];
    int base = blockIdx.x * 1024;
    int tid = threadIdx.x;
    int sum = 0;
    #pragma unroll
    for (int j = 0; j < 4; ++j) { int i = base + j * 256 + tid; if (i < E) sum += counts[i]; }
    s[tid] = sum; __syncthreads();
    for (int off = 128; off > 0; off >>= 1) {
        if (tid < off) s[tid] += s[tid + off];
        __syncthreads();
    }
    if (tid == 0) bsum[blockIdx.x] = s[0];
}

__global__ __launch_bounds__(512) void psum2_k(int* bsum, int G) {
    __shared__ int s[512];
    int tid = threadIdx.x;
    s[tid] = (tid < G) ? bsum[tid] : 0;
    for (int off = 1; off < 512; off <<= 1) {
        __syncthreads();
        int v = (tid >= off) ? s[tid - off] : 0;
        __syncthreads();
        s[tid] += v;
    }
    __syncthreads();
    if (tid < G) bsum[tid] = (tid == 0) ? 0 : s[tid - 1];
}

__global__ __launch_bounds__(256) void psum3_k(const int* __restrict__ counts,
                                               const int* __restrict__ bsum,
                                               int* __restrict__ start, int E) {
    __shared__ int s[256];
    int tid = threadIdx.x;
    int base = blockIdx.x * 1024 + tid * 4;
    int v[4]; int loc = 0;
    #pragma unroll
    for (int j = 0; j < 4; ++j) { v[j] = (base + j < E) ? counts[base + j] : 0; loc += v[j]; }
    s[tid] = loc;
    for (int off = 1; off < 256; off <<= 1) {
        __syncthreads();
        int t2 = (tid >= off) ? s[tid - off] : 0;
        __syncthreads();
        s[tid] += t2;
    }
    __syncthreads();
    int run = bsum[blockIdx.x] + s[tid] - loc;
    #pragma unroll
    for (int j = 0; j < 4; ++j) { if (base + j < E) start[base + j] = run; run += v[j]; }
}

__global__ __launch_bounds__(256) void fill_k(const int* __restrict__ idx_ji,
                                              int* __restrict__ start,
                                              int* __restrict__ trip, int T) {
    int t = blockIdx.x * 256 + threadIdx.x;
    if (t >= T) return;
    int pos = atomicAdd(&start[idx_ji[t]], 1);
    trip[pos] = t;
}

// One wave per edge, lane = channel. 4-way unrolled (MLP), shuffle-free:
// pB row (16B, wave-uniform) is broadcast-loaded and unpacked in-register.
__global__ __launch_bounds__(256) void gather_k(
    const int* __restrict__ trip, const int* __restrict__ idx_kj,
    const unsigned short* __restrict__ pB, const unsigned short* __restrict__ x64b,
    const int* __restrict__ start, const int* __restrict__ counts,
    const float* __restrict__ w2, unsigned short* __restrict__ aggB, int E)
{
    int tid = threadIdx.x;
    int wave = (blockIdx.x * 256 + tid) >> 6;
    int lane = tid & 63;
    if (wave >= E) return;

    float wcol[8];
    #pragma unroll
    for (int b = 0; b < 8; ++b) wcol[b] = w2[b * 64 + lane];

    int n = counts[wave];
    int end = start[wave];
    int i = end - n;

    float acc = 0.f;
    for (; i + 4 <= end; i += 4) {
        int t0 = trip[i], t1 = trip[i + 1], t2 = trip[i + 2], t3 = trip[i + 3];
        int k0 = idx_kj[t0], k1 = idx_kj[t1], k2 = idx_kj[t2], k3 = idx_kj[t3];
        uint4 q0 = *(const uint4*)(pB + (size_t)t0 * 8);
        uint4 q1 = *(const uint4*)(pB + (size_t)t1 * 8);
        uint4 q2 = *(const uint4*)(pB + (size_t)t2 * 8);
        uint4 q3 = *(const uint4*)(pB + (size_t)t3 * 8);
        float x0 = bf2f(x64b[(size_t)k0 * ICH + lane]);
        float x1 = bf2f(x64b[(size_t)k1 * ICH + lane]);
        float x2 = bf2f(x64b[(size_t)k2 * ICH + lane]);
        float x3 = bf2f(x64b[(size_t)k3 * ICH + lane]);
        float s0 = lo16(q0.x)*wcol[0] + hi16(q0.x)*wcol[1] + lo16(q0.y)*wcol[2] + hi16(q0.y)*wcol[3]
                 + lo16(q0.z)*wcol[4] + hi16(q0.z)*wcol[5] + lo16(q0.w)*wcol[6] + hi16(q0.w)*wcol[7];
        float s1 = lo16(q1.x)*wcol[0] + hi16(q1.x)*wcol[1] + lo16(q1.y)*wcol[2] + hi16(q1.y)*wcol[3]
                 + lo16(q1.z)*wcol[4] + hi16(q1.z)*wcol[5] + lo16(q1.w)*wcol[6] + hi16(q1.w)*wcol[7];
        float s2 = lo16(q2.x)*wcol[0] + hi16(q2.x)*wcol[1] + lo16(q2.y)*wcol[2] + hi16(q2.y)*wcol[3]
                 + lo16(q2.z)*wcol[4] + hi16(q2.z)*wcol[5] + lo16(q2.w)*wcol[6] + hi16(q2.w)*wcol[7];
        float s3 = lo16(q3.x)*wcol[0] + hi16(q3.x)*wcol[1] + lo16(q3.y)*wcol[2] + hi16(q3.y)*wcol[3]
                 + lo16(q3.z)*wcol[4] + hi16(q3.z)*wcol[5] + lo16(q3.w)*wcol[6] + hi16(q3.w)*wcol[7];
        acc += s0 * x0 + s1 * x1 + s2 * x2 + s3 * x3;
    }
    for (; i < end; ++i) {
        int t = trip[i];
        int kj = idx_kj[t];
        uint4 q = *(const uint4*)(pB + (size_t)t * 8);
        float xv = bf2f(x64b[(size_t)kj * ICH + lane]);
        float sc = lo16(q.x)*wcol[0] + hi16(q.x)*wcol[1] + lo16(q.y)*wcol[2] + hi16(q.y)*wcol[3]
                 + lo16(q.z)*wcol[4] + hi16(q.z)*wcol[5] + lo16(q.w)*wcol[6] + hi16(q.w)*wcol[7];
        acc += sc * xv;
    }
    aggB[(size_t)wave * ICH + lane] = f2bf(acc);
}

extern "C" void kernel_launch(void* const* d_in, const int* in_sizes, int n_in,
                              void* d_out, int out_size, void* d_ws, size_t ws_size,
                              hipStream_t stream) {
    const float* x      = (const float*)d_in[0];
    const float* rbf    = (const float*)d_in[1];
    const float* sbf    = (const float*)d_in[2];
    const int*   idx_kj = (const int*)d_in[3];
    const int*   idx_ji = (const int*)d_in[4];
    const float* W_rbf1 = (const float*)d_in[5];
    const float* W_rbf2 = (const float*)d_in[6];
    const float* W_sbf1 = (const float*)d_in[7];
    const float* W_sbf2 = (const float*)d_in[8];
    const float* W_kj   = (const float*)d_in[9];
    const float* b_kj   = (const float*)d_in[10];
    const float* W_ji   = (const float*)d_in[11];
    const float* b_ji   = (const float*)d_in[12];
    const float* W_down = (const float*)d_in[13];
    const float* W_up   = (const float*)d_in[14];
    const float* resbW  = (const float*)d_in[15];
    const float* resbB  = (const float*)d_in[16];
    const float* W_lin  = (const float*)d_in[17];
    const float* b_lin  = (const float*)d_in[18];
    const float* resaW  = (const float*)d_in[19];
    const float* resaB  = (const float*)d_in[20];

    const int E = in_sizes[0] / HCH;
    const int T = in_sizes[3];
    float* out = (float*)d_out;

    // ws: wc_rbf f32[1152] | counts[E] | start[E] | bsum[512] | trip[T] |
    //     pB u16[T*8] | x64b u16[E*64] | aggB u16[E*64] | Wt u16[WT_TOTAL]
    float* wc_rbf = (float*)d_ws;
    int*   counts = (int*)(wc_rbf + NRAD * HCH);
    int*   start  = counts + E;
    int*   bsum   = start + E;
    int*   trip   = bsum + 512;
    unsigned short* pB   = (unsigned short*)(trip + T);
    unsigned short* x64b = pB + (size_t)T * 8;
    unsigned short* aggB = x64b + (size_t)E * ICH;
    unsigned short* Wt   = aggB + (size_t)E * ICH;

    const unsigned short* Wt_kj   = Wt;
    const unsigned short* Wt_ji   = Wt + 1 * WSEG;
    const unsigned short* Wt_lin  = Wt + 2 * WSEG;
    const unsigned short* Wt_rb0  = Wt + 3 * WSEG;   // W0, W1 at +WSEG
    const unsigned short* Wt_ra   = Wt + 5 * WSEG;   // ra0_0, ra0_1, ra1_0, ra1_1
    const unsigned short* Wt_down = Wt + WT_DOWN;
    const unsigned short* Wt_up   = Wt + WT_UP;

    const int gb64  = (E + 63) / 64;
    const int gb128 = (E + 127) / 128;
    const int gt = (T + 255) / 256;
    const int gscan = (E + 1023) / 1024;

    wc_k<<<(NRAD * HCH + NT - 1) / NT, NT, 0, stream>>>(W_rbf1, W_rbf2, wc_rbf);
    prep_k<<<(WT_TOTAL + NT - 1) / NT, NT, 0, stream>>>(W_kj, W_ji, W_lin, resbW, resaW,
                                                        W_down, W_up, Wt);

    // CSR build
    hipMemsetAsync(counts, 0, (size_t)E * sizeof(int), stream);
    pcount_k<<<gt, 256, 0, stream>>>(sbf, idx_ji, W_sbf1, pB, counts, T);
    psum1_k<<<gscan, 256, 0, stream>>>(counts, bsum, E);
    psum2_k<<<1, 512, 0, stream>>>(bsum, gscan);
    psum3_k<<<gscan, 256, 0, stream>>>(counts, bsum, start, E);
    fill_k<<<gt, 256, 0, stream>>>(idx_ji, start, trip, T);

    // x -> x64b (bf16)
    fused12_k<<<gb64, NT, 0, stream>>>(x, Wt_kj, b_kj, rbf, wc_rbf, Wt_down, x64b, E);
    // aggB = segment_sum(x64b[idx_kj] * (p@W_sbf2), idx_ji)   (bf16 out)
    gather_k<<<(E + 3) / 4, 256, 0, stream>>>(trip, idx_kj, pB, x64b, start, counts, W_sbf2, aggB, E);
    // h = silu(x@W_ji+b) + silu(agg@W_up)
    combine_k<<<gb64, NT, 0, stream>>>(x, Wt_ji, b_ji, aggB, Wt_up, out, E);
    // res_before
    res_k<<<gb128, NT, 0, stream>>>(out, Wt_rb0, Wt_rb0 + WSEG, resbB, resbB + HCH, E);
    // h = silu(h@W_lin + b_lin) + x
    lin_k<<<gb128, NT, 0, stream>>>(out, Wt_lin, b_lin, x, E);
    // res_after x2
    res_k<<<gb128, NT, 0, stream>>>(out, Wt_ra, Wt_ra + WSEG, resaB, resaB + HCH, E);
    res_k<<<gb128, NT, 0, stream>>>(out, Wt_ra + 2 * WSEG, Wt_ra + 3 * WSEG,
                                    resaB + 2 * HCH, resaB + 3 * HCH, E);
}

// Round 7
// 3062.888 us; speedup vs baseline: 1.4551x; 1.1241x over previous
//
#include <hip/hip_runtime.h>
#include <cstdint>
#include <cstddef>

#define HCH 192
#define ICH 64
#define NRAD 6
#define SBFD 42

constexpr int NT = 256;

using bfrag = __attribute__((ext_vector_type(8))) short;  // 8 bf16 (4 VGPRs)
using f32x4 = __attribute__((ext_vector_type(4))) float;

#define MFMA16(a, b, c) __builtin_amdgcn_mfma_f32_16x16x32_bf16(a, b, c, 0, 0, 0)

__device__ __forceinline__ float silu_f(float v) {
    return v / (1.0f + __expf(-v));
}

__device__ __forceinline__ unsigned short f2bf(float x) {
    union { float f; unsigned u; } v; v.f = x;
    return (unsigned short)((v.u + 0x7FFFu + ((v.u >> 16) & 1u)) >> 16);
}

__device__ __forceinline__ float bf2f(unsigned short u) {
    union { unsigned u; float f; } v; v.u = ((unsigned)u) << 16;
    return v.f;
}

__device__ __forceinline__ float lo16(unsigned u) {
    union { unsigned x; float f; } v; v.x = u << 16; return v.f;
}
__device__ __forceinline__ float hi16(unsigned u) {
    union { unsigned x; float f; } v; v.x = u & 0xffff0000u; return v.f;
}

__device__ __forceinline__ bfrag pack8(float4 a, float4 b) {
    bfrag r;
    r[0] = (short)f2bf(a.x); r[1] = (short)f2bf(a.y);
    r[2] = (short)f2bf(a.z); r[3] = (short)f2bf(a.w);
    r[4] = (short)f2bf(b.x); r[5] = (short)f2bf(b.y);
    r[6] = (short)f2bf(b.z); r[7] = (short)f2bf(b.w);
    return r;
}

__device__ __forceinline__ bfrag bzero() {
    bfrag r;
    #pragma unroll
    for (int i = 0; i < 8; ++i) r[i] = 0;
    return r;
}

// ---------------- weight prep: fp32 [K][N] -> bf16 transposed [N][K] ----------------
#define WSEG 36864
#define WT_DOWN (9 * WSEG)
#define WT_UP   (9 * WSEG + 12288)
#define WT_TOTAL (9 * WSEG + 2 * 12288)

__global__ __launch_bounds__(NT) void prep_k(
    const float* __restrict__ W_kj, const float* __restrict__ W_ji,
    const float* __restrict__ W_lin, const float* __restrict__ resbW,
    const float* __restrict__ resaW, const float* __restrict__ W_down,
    const float* __restrict__ W_up, unsigned short* __restrict__ Wt)
{
    int i = blockIdx.x * NT + threadIdx.x;
    if (i < 9 * WSEG) {
        int seg = i / WSEG, r = i % WSEG;
        int k = r / HCH, n = r % HCH;
        const float* src =
            seg == 0 ? W_kj : seg == 1 ? W_ji : seg == 2 ? W_lin :
            seg <= 4 ? resbW + (seg - 3) * WSEG : resaW + (seg - 5) * WSEG;
        Wt[seg * WSEG + n * HCH + k] = f2bf(src[r]);
    } else if (i < WT_DOWN + 12288) {
        int r = i - WT_DOWN;
        int k = r / ICH, n = r % ICH;           // W_down [192][64]
        Wt[WT_DOWN + n * HCH + k] = f2bf(W_down[r]);
    } else if (i < WT_TOTAL) {
        int r = i - WT_UP;
        int k = r / HCH, n = r % HCH;           // W_up [64][192]
        Wt[WT_UP + n * ICH + k] = f2bf(W_up[r]);
    }
}

// wc_rbf[6,192] = W_rbf1[6,8] @ W_rbf2[8,192]  (kept fp32)
__global__ void wc_k(const float* __restrict__ W_rbf1, const float* __restrict__ W_rbf2,
                     float* __restrict__ wc)
{
    int tid = blockIdx.x * blockDim.x + threadIdx.x;
    if (tid < NRAD * HCH) {
        int r = tid / HCH, c = tid % HCH;
        float a = 0.f;
        #pragma unroll
        for (int b = 0; b < 8; ++b) a += W_rbf1[r * 8 + b] * W_rbf2[b * HCH + c];
        wc[tid] = a;
    }
}

// ---------------- head: x -> x64b (bf16) : W_kj + rbf modulate + W_down ----------------
__global__ __launch_bounds__(NT) void fused12_k(
    const float* __restrict__ x, const unsigned short* __restrict__ Wt_kj,
    const float* __restrict__ b_kj, const float* __restrict__ rbf,
    const float* __restrict__ wc, const unsigned short* __restrict__ Wt_down,
    unsigned short* __restrict__ x64b, int E)
{
    __shared__ unsigned short u_s[64][200];
    __shared__ float wc_s[NRAD * HCH];
    const int tid = threadIdx.x;
    const int lane = tid & 63, w = tid >> 6;
    const int row0 = blockIdx.x * 64;
    const int lr = lane & 15, lq = lane >> 4;
    const int kq = lq * 8;

    for (int i = tid; i < NRAD * HCH; i += NT) wc_s[i] = wc[i];

    const int ra = row0 + w * 16 + lr;
    const bool rav = ra < E;

    f32x4 acc[12];
    #pragma unroll
    for (int t = 0; t < 12; ++t) acc[t] = (f32x4){0.f, 0.f, 0.f, 0.f};

    #pragma unroll
    for (int ks = 0; ks < 6; ++ks) {
        const int k0 = ks * 32;
        float4 a0 = make_float4(0,0,0,0), a1 = make_float4(0,0,0,0);
        if (rav) {
            a0 = *(const float4*)(x + (size_t)ra * HCH + k0 + kq);
            a1 = *(const float4*)(x + (size_t)ra * HCH + k0 + kq + 4);
        }
        bfrag a = pack8(a0, a1);
        #pragma unroll
        for (int t = 0; t < 12; ++t) {
            bfrag b = *(const bfrag*)(Wt_kj + (size_t)(t * 16 + lr) * HCH + k0 + kq);
            acc[t] = MFMA16(a, b, acc[t]);
        }
    }
    __syncthreads();   // wc_s ready
    #pragma unroll
    for (int r = 0; r < 4; ++r) {
        int rloc = lq * 4 + r;
        int grow = row0 + w * 16 + rloc;
        float rb[NRAD];
        #pragma unroll
        for (int q = 0; q < NRAD; ++q) rb[q] = 0.f;
        if (grow < E) {
            #pragma unroll
            for (int q = 0; q < NRAD; ++q) rb[q] = rbf[(size_t)grow * NRAD + q];
        }
        #pragma unroll
        for (int t = 0; t < 12; ++t) {
            int col = t * 16 + lr;
            float sv = silu_f(acc[t][r] + b_kj[col]);
            float rh = 0.f;
            #pragma unroll
            for (int q = 0; q < NRAD; ++q) rh += rb[q] * wc_s[q * HCH + col];
            u_s[w * 16 + rloc][col] = f2bf(sv * rh);
        }
    }
    __syncthreads();   // u_s visible (cross-lane)

    f32x4 acc2[4];
    #pragma unroll
    for (int t = 0; t < 4; ++t) acc2[t] = (f32x4){0.f, 0.f, 0.f, 0.f};
    #pragma unroll
    for (int ks = 0; ks < 6; ++ks) {
        const int k0 = ks * 32;
        bfrag a = *(const bfrag*)&u_s[w * 16 + lr][k0 + kq];
        #pragma unroll
        for (int t = 0; t < 4; ++t) {
            bfrag b = *(const bfrag*)(Wt_down + (size_t)(t * 16 + lr) * HCH + k0 + kq);
            acc2[t] = MFMA16(a, b, acc2[t]);
        }
    }
    #pragma unroll
    for (int r = 0; r < 4; ++r) {
        int grow = row0 + w * 16 + lq * 4 + r;
        if (grow >= E) continue;
        #pragma unroll
        for (int t = 0; t < 4; ++t)
            x64b[(size_t)grow * ICH + t * 16 + lr] = f2bf(silu_f(acc2[t][r]));
    }
}

// ---------------- tail kernels (h carried as bf16 in hB) ----------------

// hB = bf16( silu(x@W_ji + b_ji) + silu(agg@W_up) )
__global__ __launch_bounds__(NT) void combine_k(
    const float* __restrict__ x, const unsigned short* __restrict__ Wt_ji,
    const float* __restrict__ b_ji, const unsigned short* __restrict__ aggB,
    const unsigned short* __restrict__ Wt_up, unsigned short* __restrict__ hB, int E)
{
    const int tid = threadIdx.x;
    const int lane = tid & 63, w = tid >> 6;
    const int row0 = blockIdx.x * 64;
    const int lr = lane & 15, lq = lane >> 4;
    const int kq = lq * 8;
    const int ra = row0 + w * 16 + lr;
    const bool rav = ra < E;

    f32x4 acc[12], acc2[12];
    #pragma unroll
    for (int t = 0; t < 12; ++t) {
        acc[t] = (f32x4){0.f, 0.f, 0.f, 0.f};
        acc2[t] = (f32x4){0.f, 0.f, 0.f, 0.f};
    }

    #pragma unroll
    for (int ks = 0; ks < 6; ++ks) {
        const int k0 = ks * 32;
        float4 a0 = make_float4(0,0,0,0), a1 = make_float4(0,0,0,0);
        if (rav) {
            a0 = *(const float4*)(x + (size_t)ra * HCH + k0 + kq);
            a1 = *(const float4*)(x + (size_t)ra * HCH + k0 + kq + 4);
        }
        bfrag a = pack8(a0, a1);
        #pragma unroll
        for (int t = 0; t < 12; ++t) {
            bfrag b = *(const bfrag*)(Wt_ji + (size_t)(t * 16 + lr) * HCH + k0 + kq);
            acc[t] = MFMA16(a, b, acc[t]);
        }
    }
    #pragma unroll
    for (int ks = 0; ks < 2; ++ks) {
        const int k0 = ks * 32;
        bfrag a = rav ? *(const bfrag*)(aggB + (size_t)ra * ICH + k0 + kq) : bzero();
        #pragma unroll
        for (int t = 0; t < 12; ++t) {
            bfrag b = *(const bfrag*)(Wt_up + (size_t)(t * 16 + lr) * ICH + k0 + kq);
            acc2[t] = MFMA16(a, b, acc2[t]);
        }
    }
    #pragma unroll
    for (int r = 0; r < 4; ++r) {
        int grow = row0 + w * 16 + lq * 4 + r;
        if (grow >= E) continue;
        #pragma unroll
        for (int t = 0; t < 12; ++t) {
            int col = t * 16 + lr;
            hB[(size_t)grow * HCH + col] =
                f2bf(silu_f(acc[t][r] + b_ji[col]) + silu_f(acc2[t][r]));
        }
    }
}

// residual layer on bf16 h, 128 rows/block (32/wave).
// FINAL=0: hB += silu(...) in-place (bf16). FINAL=1: out(fp32) = hB + silu(...).
template<int FINAL>
__global__ __launch_bounds__(NT) void res_k(
    unsigned short* __restrict__ hB, const unsigned short* __restrict__ Wt0,
    const unsigned short* __restrict__ Wt1, const float* __restrict__ b0,
    const float* __restrict__ b1, float* __restrict__ out, int E)
{
    __shared__ unsigned short t_s[128][200];
    const int tid = threadIdx.x;
    const int lane = tid & 63, w = tid >> 6;
    const int row0 = blockIdx.x * 128;
    const int wbase = w * 32;
    const int lr = lane & 15, lq = lane >> 4;
    const int kq = lq * 8;

    f32x4 acc[2][12];
    #pragma unroll
    for (int g = 0; g < 2; ++g)
        #pragma unroll
        for (int t = 0; t < 12; ++t) acc[g][t] = (f32x4){0.f, 0.f, 0.f, 0.f};

    // GEMM 1: A direct bf16 load from hB (own rows), B shared across row-groups
    #pragma unroll
    for (int ks = 0; ks < 6; ++ks) {
        const int k0 = ks * 32;
        bfrag afr[2];
        #pragma unroll
        for (int g = 0; g < 2; ++g) {
            int row = row0 + wbase + g * 16 + lr;
            afr[g] = (row < E) ? *(const bfrag*)(hB + (size_t)row * HCH + k0 + kq)
                               : bzero();
        }
        #pragma unroll
        for (int t = 0; t < 12; ++t) {
            bfrag b = *(const bfrag*)(Wt0 + (size_t)(t * 16 + lr) * HCH + k0 + kq);
            acc[0][t] = MFMA16(afr[0], b, acc[0][t]);
            acc[1][t] = MFMA16(afr[1], b, acc[1][t]);
        }
    }
    #pragma unroll
    for (int g = 0; g < 2; ++g)
        #pragma unroll
        for (int r = 0; r < 4; ++r) {
            int rloc = wbase + g * 16 + lq * 4 + r;
            #pragma unroll
            for (int t = 0; t < 12; ++t) {
                int col = t * 16 + lr;
                t_s[rloc][col] = f2bf(silu_f(acc[g][t][r] + b0[col]));
            }
        }
    __syncthreads();

    #pragma unroll
    for (int g = 0; g < 2; ++g)
        #pragma unroll
        for (int t = 0; t < 12; ++t) acc[g][t] = (f32x4){0.f, 0.f, 0.f, 0.f};

    // GEMM 2: A from t_s
    #pragma unroll
    for (int ks = 0; ks < 6; ++ks) {
        const int k0 = ks * 32;
        bfrag afr0 = *(const bfrag*)&t_s[wbase + lr][k0 + kq];
        bfrag afr1 = *(const bfrag*)&t_s[wbase + 16 + lr][k0 + kq];
        #pragma unroll
        for (int t = 0; t < 12; ++t) {
            bfrag b = *(const bfrag*)(Wt1 + (size_t)(t * 16 + lr) * HCH + k0 + kq);
            acc[0][t] = MFMA16(afr0, b, acc[0][t]);
            acc[1][t] = MFMA16(afr1, b, acc[1][t]);
        }
    }
    #pragma unroll
    for (int g = 0; g < 2; ++g)
        #pragma unroll
        for (int r = 0; r < 4; ++r) {
            int grow = row0 + wbase + g * 16 + lq * 4 + r;
            if (grow >= E) continue;
            #pragma unroll
            for (int t = 0; t < 12; ++t) {
                int col = t * 16 + lr;
                size_t off = (size_t)grow * HCH + col;
                float v = bf2f(hB[off]) + silu_f(acc[g][t][r] + b1[col]);
                if (FINAL) out[off] = v;
                else       hB[off] = f2bf(v);
            }
        }
}

// hB = bf16( silu(hB@W_lin + b_lin) + x ), 128 rows/block
__global__ __launch_bounds__(NT) void lin_k(
    unsigned short* __restrict__ hB, const unsigned short* __restrict__ Wt_lin,
    const float* __restrict__ b_lin, const float* __restrict__ x, int E)
{
    const int tid = threadIdx.x;
    const int lane = tid & 63, w = tid >> 6;
    const int row0 = blockIdx.x * 128;
    const int wbase = w * 32;
    const int lr = lane & 15, lq = lane >> 4;
    const int kq = lq * 8;

    f32x4 acc[2][12];
    #pragma unroll
    for (int g = 0; g < 2; ++g)
        #pragma unroll
        for (int t = 0; t < 12; ++t) acc[g][t] = (f32x4){0.f, 0.f, 0.f, 0.f};

    #pragma unroll
    for (int ks = 0; ks < 6; ++ks) {
        const int k0 = ks * 32;
        bfrag afr[2];
        #pragma unroll
        for (int g = 0; g < 2; ++g) {
            int row = row0 + wbase + g * 16 + lr;
            afr[g] = (row < E) ? *(const bfrag*)(hB + (size_t)row * HCH + k0 + kq)
                               : bzero();
        }
        #pragma unroll
        for (int t = 0; t < 12; ++t) {
            bfrag b = *(const bfrag*)(Wt_lin + (size_t)(t * 16 + lr) * HCH + k0 + kq);
            acc[0][t] = MFMA16(afr[0], b, acc[0][t]);
            acc[1][t] = MFMA16(afr[1], b, acc[1][t]);
        }
    }
    #pragma unroll
    for (int g = 0; g < 2; ++g)
        #pragma unroll
        for (int r = 0; r < 4; ++r) {
            int grow = row0 + wbase + g * 16 + lq * 4 + r;
            if (grow >= E) continue;
            #pragma unroll
            for (int t = 0; t < 12; ++t) {
                int col = t * 16 + lr;
                size_t off = (size_t)grow * HCH + col;
                hB[off] = f2bf(silu_f(acc[g][t][r] + b_lin[col]) + x[off]);
            }
        }
}

// ---------------- CSR scatter->gather pipeline ----------------
__global__ __launch_bounds__(256) void pcount_k(
    const float* __restrict__ sbf, const int* __restrict__ idx_ji,
    const float* __restrict__ w1, unsigned short* __restrict__ pB,
    int* __restrict__ counts, int T)
{
    int t = blockIdx.x * 256 + threadIdx.x;
    if (t >= T) return;
    const float* sp = sbf + (size_t)t * SBFD;
    float acc[8];
    #pragma unroll
    for (int b = 0; b < 8; ++b) acc[b] = 0.f;
    #pragma unroll
    for (int r = 0; r < SBFD; r += 2) {
        float2 v = *(const float2*)(sp + r);
        #pragma unroll
        for (int b = 0; b < 8; ++b)
            acc[b] += v.x * w1[r * 8 + b] + v.y * w1[(r + 1) * 8 + b];
    }
    uint4 pk;
    pk.x = (unsigned)f2bf(acc[0]) | ((unsigned)f2bf(acc[1]) << 16);
    pk.y = (unsigned)f2bf(acc[2]) | ((unsigned)f2bf(acc[3]) << 16);
    pk.z = (unsigned)f2bf(acc[4]) | ((unsigned)f2bf(acc[5]) << 16);
    pk.w = (unsigned)f2bf(acc[6]) | ((unsigned)f2bf(acc[7]) << 16);
    *(uint4*)(pB + (size_t)t * 8) = pk;
    atomicAdd(&counts[idx_ji[t]], 1);
}

__global__ __launch_bounds__(256) void psum1_k(const int* __restrict__ counts,
                                               int* __restrict__ bsum, int E) {
    __shared__ int s[256];
    int base = blockIdx.x * 1024;
    int tid = threadIdx.x;
    int sum = 0;
    #pragma unroll
    for (int j = 0; j < 4; ++j) { int i = base + j * 256 + tid; if (i < E) sum += counts[i]; }
    s[tid] = sum; __syncthreads();
    for (int off = 128; off > 0; off >>= 1) {
        if (tid < off) s[tid] += s[tid + off];
        __syncthreads();
    }
    if (tid == 0) bsum[blockIdx.x] = s[0];
}

__global__ __launch_bounds__(512) void psum2_k(int* bsum, int G) {
    __shared__ int s[512];
    int tid = threadIdx.x;
    s[tid] = (tid < G) ? bsum[tid] : 0;
    for (int off = 1; off < 512; off <<= 1) {
        __syncthreads();
        int v = (tid >= off) ? s[tid - off] : 0;
        __syncthreads();
        s[tid] += v;
    }
    __syncthreads();
    if (tid < G) bsum[tid] = (tid == 0) ? 0 : s[tid - 1];
}

__global__ __launch_bounds__(256) void psum3_k(const int* __restrict__ counts,
                                               const int* __restrict__ bsum,
                                               int* __restrict__ start, int E) {
    __shared__ int s[256];
    int tid = threadIdx.x;
    int base = blockIdx.x * 1024 + tid * 4;
    int v[4]; int loc = 0;
    #pragma unroll
    for (int j = 0; j < 4; ++j) { v[j] = (base + j < E) ? counts[base + j] : 0; loc += v[j]; }
    s[tid] = loc;
    for (int off = 1; off < 256; off <<= 1) {
        __syncthreads();
        int t2 = (tid >= off) ? s[tid - off] : 0;
        __syncthreads();
        s[tid] += t2;
    }
    __syncthreads();
    int run = bsum[blockIdx.x] + s[tid] - loc;
    #pragma unroll
    for (int j = 0; j < 4; ++j) { if (base + j < E) start[base + j] = run; run += v[j]; }
}

__global__ __launch_bounds__(256) void fill_k(const int* __restrict__ idx_ji,
                                              int* __restrict__ start,
                                              int* __restrict__ trip, int T) {
    int t = blockIdx.x * 256 + threadIdx.x;
    if (t >= T) return;
    int pos = atomicAdd(&start[idx_ji[t]], 1);
    trip[pos] = t;
}

// One wave per edge, lane = channel. 4-way unrolled (MLP), shuffle-free.
__global__ __launch_bounds__(256) void gather_k(
    const int* __restrict__ trip, const int* __restrict__ idx_kj,
    const unsigned short* __restrict__ pB, const unsigned short* __restrict__ x64b,
    const int* __restrict__ start, const int* __restrict__ counts,
    const float* __restrict__ w2, unsigned short* __restrict__ aggB, int E)
{
    int tid = threadIdx.x;
    int wave = (blockIdx.x * 256 + tid) >> 6;
    int lane = tid & 63;
    if (wave >= E) return;

    float wcol[8];
    #pragma unroll
    for (int b = 0; b < 8; ++b) wcol[b] = w2[b * 64 + lane];

    int n = counts[wave];
    int end = start[wave];
    int i = end - n;

    float acc = 0.f;
    for (; i + 4 <= end; i += 4) {
        int t0 = trip[i], t1 = trip[i + 1], t2 = trip[i + 2], t3 = trip[i + 3];
        int k0 = idx_kj[t0], k1 = idx_kj[t1], k2 = idx_kj[t2], k3 = idx_kj[t3];
        uint4 q0 = *(const uint4*)(pB + (size_t)t0 * 8);
        uint4 q1 = *(const uint4*)(pB + (size_t)t1 * 8);
        uint4 q2 = *(const uint4*)(pB + (size_t)t2 * 8);
        uint4 q3 = *(const uint4*)(pB + (size_t)t3 * 8);
        float x0 = bf2f(x64b[(size_t)k0 * ICH + lane]);
        float x1 = bf2f(x64b[(size_t)k1 * ICH + lane]);
        float x2 = bf2f(x64b[(size_t)k2 * ICH + lane]);
        float x3 = bf2f(x64b[(size_t)k3 * ICH + lane]);
        float s0 = lo16(q0.x)*wcol[0] + hi16(q0.x)*wcol[1] + lo16(q0.y)*wcol[2] + hi16(q0.y)*wcol[3]
                 + lo16(q0.z)*wcol[4] + hi16(q0.z)*wcol[5] + lo16(q0.w)*wcol[6] + hi16(q0.w)*wcol[7];
        float s1 = lo16(q1.x)*wcol[0] + hi16(q1.x)*wcol[1] + lo16(q1.y)*wcol[2] + hi16(q1.y)*wcol[3]
                 + lo16(q1.z)*wcol[4] + hi16(q1.z)*wcol[5] + lo16(q1.w)*wcol[6] + hi16(q1.w)*wcol[7];
        float s2 = lo16(q2.x)*wcol[0] + hi16(q2.x)*wcol[1] + lo16(q2.y)*wcol[2] + hi16(q2.y)*wcol[3]
                 + lo16(q2.z)*wcol[4] + hi16(q2.z)*wcol[5] + lo16(q2.w)*wcol[6] + hi16(q2.w)*wcol[7];
        float s3 = lo16(q3.x)*wcol[0] + hi16(q3.x)*wcol[1] + lo16(q3.y)*wcol[2] + hi16(q3.y)*wcol[3]
                 + lo16(q3.z)*wcol[4] + hi16(q3.z)*wcol[5] + lo16(q3.w)*wcol[6] + hi16(q3.w)*wcol[7];
        acc += s0 * x0 + s1 * x1 + s2 * x2 + s3 * x3;
    }
    for (; i < end; ++i) {
        int t = trip[i];
        int kj = idx_kj[t];
        uint4 q = *(const uint4*)(pB + (size_t)t * 8);
        float xv = bf2f(x64b[(size_t)kj * ICH + lane]);
        float sc = lo16(q.x)*wcol[0] + hi16(q.x)*wcol[1] + lo16(q.y)*wcol[2] + hi16(q.y)*wcol[3]
                 + lo16(q.z)*wcol[4] + hi16(q.z)*wcol[5] + lo16(q.w)*wcol[6] + hi16(q.w)*wcol[7];
        acc += sc * xv;
    }
    aggB[(size_t)wave * ICH + lane] = f2bf(acc);
}

extern "C" void kernel_launch(void* const* d_in, const int* in_sizes, int n_in,
                              void* d_out, int out_size, void* d_ws, size_t ws_size,
                              hipStream_t stream) {
    const float* x      = (const float*)d_in[0];
    const float* rbf    = (const float*)d_in[1];
    const float* sbf    = (const float*)d_in[2];
    const int*   idx_kj = (const int*)d_in[3];
    const int*   idx_ji = (const int*)d_in[4];
    const float* W_rbf1 = (const float*)d_in[5];
    const float* W_rbf2 = (const float*)d_in[6];
    const float* W_sbf1 = (const float*)d_in[7];
    const float* W_sbf2 = (const float*)d_in[8];
    const float* W_kj   = (const float*)d_in[9];
    const float* b_kj   = (const float*)d_in[10];
    const float* W_ji   = (const float*)d_in[11];
    const float* b_ji   = (const float*)d_in[12];
    const float* W_down = (const float*)d_in[13];
    const float* W_up   = (const float*)d_in[14];
    const float* resbW  = (const float*)d_in[15];
    const float* resbB  = (const float*)d_in[16];
    const float* W_lin  = (const float*)d_in[17];
    const float* b_lin  = (const float*)d_in[18];
    const float* resaW  = (const float*)d_in[19];
    const float* resaB  = (const float*)d_in[20];

    const int E = in_sizes[0] / HCH;
    const int T = in_sizes[3];
    float* out = (float*)d_out;

    // ws: wc_rbf f32[1152] | counts[E] | start[E] | bsum[512] | trip[T] |
    //     pB u16[T*8] | x64b u16[E*64] | aggB u16[E*64] | hB u16[E*192] | Wt u16
    float* wc_rbf = (float*)d_ws;
    int*   counts = (int*)(wc_rbf + NRAD * HCH);
    int*   start  = counts + E;
    int*   bsum   = start + E;
    int*   trip   = bsum + 512;
    unsigned short* pB   = (unsigned short*)(trip + T);
    unsigned short* x64b = pB + (size_t)T * 8;
    unsigned short* aggB = x64b + (size_t)E * ICH;
    unsigned short* hB   = aggB + (size_t)E * ICH;
    unsigned short* Wt   = hB + (size_t)E * HCH;

    const unsigned short* Wt_kj   = Wt;
    const unsigned short* Wt_ji   = Wt + 1 * WSEG;
    const unsigned short* Wt_lin  = Wt + 2 * WSEG;
    const unsigned short* Wt_rb0  = Wt + 3 * WSEG;   // W0, W1 at +WSEG
    const unsigned short* Wt_ra   = Wt + 5 * WSEG;   // ra0_0, ra0_1, ra1_0, ra1_1
    const unsigned short* Wt_down = Wt + WT_DOWN;
    const unsigned short* Wt_up   = Wt + WT_UP;

    const int gb64  = (E + 63) / 64;
    const int gb128 = (E + 127) / 128;
    const int gt = (T + 255) / 256;
    const int gscan = (E + 1023) / 1024;

    wc_k<<<(NRAD * HCH + NT - 1) / NT, NT, 0, stream>>>(W_rbf1, W_rbf2, wc_rbf);
    prep_k<<<(WT_TOTAL + NT - 1) / NT, NT, 0, stream>>>(W_kj, W_ji, W_lin, resbW, resaW,
                                                        W_down, W_up, Wt);

    // CSR build
    hipMemsetAsync(counts, 0, (size_t)E * sizeof(int), stream);
    pcount_k<<<gt, 256, 0, stream>>>(sbf, idx_ji, W_sbf1, pB, counts, T);
    psum1_k<<<gscan, 256, 0, stream>>>(counts, bsum, E);
    psum2_k<<<1, 512, 0, stream>>>(bsum, gscan);
    psum3_k<<<gscan, 256, 0, stream>>>(counts, bsum, start, E);
    fill_k<<<gt, 256, 0, stream>>>(idx_ji, start, trip, T);

    // x -> x64b (bf16)
    fused12_k<<<gb64, NT, 0, stream>>>(x, Wt_kj, b_kj, rbf, wc_rbf, Wt_down, x64b, E);
    // aggB = segment_sum(x64b[idx_kj] * (p@W_sbf2), idx_ji)
    gather_k<<<(E + 3) / 4, 256, 0, stream>>>(trip, idx_kj, pB, x64b, start, counts, W_sbf2, aggB, E);
    // hB = silu(x@W_ji+b) + silu(agg@W_up)
    combine_k<<<gb64, NT, 0, stream>>>(x, Wt_ji, b_ji, aggB, Wt_up, hB, E);
    // res_before
    res_k<0><<<gb128, NT, 0, stream>>>(hB, Wt_rb0, Wt_rb0 + WSEG, resbB, resbB + HCH, out, E);
    // hB = silu(hB@W_lin + b_lin) + x
    lin_k<<<gb128, NT, 0, stream>>>(hB, Wt_lin, b_lin, x, E);
    // res_after x2 (last writes fp32 to out)
    res_k<0><<<gb128, NT, 0, stream>>>(hB, Wt_ra, Wt_ra + WSEG, resaB, resaB + HCH, out, E);
    res_k<1><<<gb128, NT, 0, stream>>>(hB, Wt_ra + 2 * WSEG, Wt_ra + 3 * WSEG,
                                       resaB + 2 * HCH, resaB + 3 * HCH, out, E);
}